// Round 1
// baseline (806.124 us; speedup 1.0000x reference)
//
#include <hip/hip_runtime.h>
#include <math.h>

// ---------------------------------------------------------------------------
// MultiGraphClassifier on MI355X.
// Pipeline: 2x GraphConv per graph + cross-graph fusion + tiny head.
// Strategy: ATOMIC-FREE CSR build via MSD radix bucketing + per-bucket LDS
// counting sort; gather-side aggregation over bf16 tables; bf16-MFMA GEMMs
// with fp32 accumulate and fused epilogues. All node intermediates
// (G,H,E,dec) bf16. conv2's H is never materialized: agg reduces per-block
// channel partials (sum/max) into a small P matrix, reduced by colsum/colmax.
// Note: softmax over a length-1 axis == 1.0, so emb = norm(a) + norm(f).
// R1: 3-phase scan. R3: atomic-free scatter. R4: bf16 MFMA + bf16 tables.
// R5: 4-wide agg unroll. R6/R7 FALSIFIED: global-atomic scope/sharding is
//   irrelevant — fixed ~21G/s memory-side RMW ceiling. R8: radix sort (no
//   global atomics). R9: SORT_T=4096 + decoupled cursor scan (786us).
// R10: bf16 intermediates + fused conv2 reductions (~345MB traffic removed).
// R11: LDS-free direct-load GEMM. A-fragments are wave-private in this tile
//   shape (4 waves x 16 rows, full N per wave) so LDS staging bought nothing;
//   B is pre-transposed to bf16 [N][K] ONCE (196KB total, L1/L2-hot) and both
//   operands load as 16B bf16x8 straight into MFMA. Kills 32 scalar
//   ds_write_b16/thread/k-tile + per-tile B conversion + both barriers.
//   K,N templated so the k-loop fully unrolls.
// ---------------------------------------------------------------------------

typedef __attribute__((ext_vector_type(8))) short bf16x8;
typedef __attribute__((ext_vector_type(8))) unsigned short u16x8;
typedef __attribute__((ext_vector_type(4))) float f32x4;

#define SORT_T 4096  // edges per phase-1 block

static __device__ inline unsigned short f2bf(float f) {
  unsigned u = __float_as_uint(f);
  unsigned r = (u + 0x7fff + ((u >> 16) & 1)) >> 16;  // RNE
  return (unsigned short)r;
}
static __device__ inline float bf2f(unsigned short h) {
  return __uint_as_float(((unsigned)h) << 16);
}

// Zero tiny accumulators + write offs sentinels. One block of 128.
__global__ void zero_small_kernel(float* __restrict__ s0, float* __restrict__ s1, int ns,
                                  float* __restrict__ ea, unsigned* __restrict__ ef, int ne,
                                  int* __restrict__ offs_a, int* __restrict__ offs_src_a,
                                  int n_a, int e_a,
                                  int* __restrict__ offs_f, int* __restrict__ offs_src_f,
                                  int n_f, int e_f) {
  int i = threadIdx.x;
  if (i < ns) { s0[i] = 0.f; s1[i] = 0.f; }
  if (i < ne) { ea[i] = 0.f; ef[i] = 0u; }
  if (i == 0) {
    offs_a[n_a] = e_a;
    offs_src_a[n_a] = e_a;
    offs_f[n_f] = e_f;
    offs_src_f[n_f] = e_f;
  }
}

// One-time weight prep: Bt[n*K + k] = bf16(W[k*N + n]) for the 6 GEMM weights.
__global__ __launch_bounds__(256) void prep_bt_kernel(
    const float* __restrict__ W_a1, const float* __restrict__ W_f1,
    const float* __restrict__ W_a2, const float* __restrict__ W_f2,
    const float* __restrict__ W1, const float* __restrict__ W2,
    unsigned short* __restrict__ T_a1, unsigned short* __restrict__ T_f1,
    unsigned short* __restrict__ T_a2, unsigned short* __restrict__ T_f2,
    unsigned short* __restrict__ T1, unsigned short* __restrict__ T2) {
  const float* src;
  unsigned short* dst;
  int K, N;
  switch (blockIdx.y) {
    case 0: src = W_a1; dst = T_a1; K = 256; N = 128; break;
    case 1: src = W_f1; dst = T_f1; K = 128; N = 128; break;
    case 2: src = W_a2; dst = T_a2; K = 128; N = 128; break;
    case 3: src = W_f2; dst = T_f2; K = 128; N = 128; break;
    case 4: src = W1;   dst = T1;   K = 128; N = 64;  break;
    default: src = W2;  dst = T2;   K = 64;  N = 128; break;
  }
  int total = K * N;
  for (int idx = blockIdx.x * 256 + threadIdx.x; idx < total; idx += gridDim.x * 256) {
    int n = idx / K, k = idx - n * K;
    dst[idx] = f2bf(src[(size_t)k * N + n]);
  }
}

// Combined key at edge i: apig -> key, fcg -> key + 65536 (18-bit space).
static __device__ inline int edge_key(const int* __restrict__ a_key,
                                      const int* __restrict__ f_key, int e_a, int i) {
  return (i < e_a) ? a_key[i] : (f_key[i - e_a] + 65536);
}

// Phase-1 histogram over high 9 bits. LDS atomics only.
__global__ __launch_bounds__(256) void radix_hist_kernel(
    const int* __restrict__ a_key, const int* __restrict__ f_key, int e_a, int E,
    int* __restrict__ blkhist, int B) {
  __shared__ int h[512];
  for (int i = threadIdx.x; i < 512; i += 256) h[i] = 0;
  __syncthreads();
  int base = blockIdx.x * SORT_T;
  int end = base + SORT_T;
  if (end > E) end = E;
  for (int i = base + threadIdx.x; i < end; i += 256)
    atomicAdd(&h[edge_key(a_key, f_key, e_a, i) >> 9], 1);
  __syncthreads();
  for (int i = threadIdx.x; i < 512; i += 256) blkhist[i * B + blockIdx.x] = h[i];
}

// One block per bin: exclusive prefix over the bin's B block-counts (in
// place) + bin total.
__global__ __launch_bounds__(256) void cursor_kernel(int* __restrict__ blkhist, int B,
                                                     int* __restrict__ bintotal) {
  __shared__ int part[256];
  int* row = blkhist + (size_t)blockIdx.x * B;
  int C = (B + 255) / 256;
  int start = threadIdx.x * C;
  int end = start + C;
  if (end > B) end = B;
  int v[8];  // C <= 8 for B <= 2048
  int s = 0;
  for (int j = start; j < end; ++j) {
    v[j - start] = row[j];
    s += v[j - start];
  }
  part[threadIdx.x] = s;
  __syncthreads();
  for (int o = 1; o < 256; o <<= 1) {
    int u = (threadIdx.x >= o) ? part[threadIdx.x - o] : 0;
    __syncthreads();
    part[threadIdx.x] += u;
    __syncthreads();
  }
  int run = part[threadIdx.x] - s;  // exclusive
  for (int j = start; j < end; ++j) {
    row[j] = run;
    run += v[j - start];
  }
  if (threadIdx.x == 255) bintotal[blockIdx.x] = part[255];
}

// Exclusive scan of 512 bin totals -> binstart. One block of 256.
__global__ __launch_bounds__(256) void binscan_kernel(const int* __restrict__ bintotal,
                                                      int* __restrict__ binstart) {
  __shared__ int x[512];
  x[threadIdx.x] = bintotal[threadIdx.x];
  x[threadIdx.x + 256] = bintotal[threadIdx.x + 256];
  __syncthreads();
  for (int o = 1; o < 512; o <<= 1) {
    int i0 = threadIdx.x, i1 = threadIdx.x + 256;
    int v0 = (i0 >= o) ? x[i0 - o] : 0;
    int v1 = (i1 >= o) ? x[i1 - o] : 0;
    __syncthreads();
    x[i0] += v0;
    x[i1] += v1;
    __syncthreads();
  }
  binstart[threadIdx.x] = x[threadIdx.x] - bintotal[threadIdx.x];
  binstart[threadIdx.x + 256] = x[threadIdx.x + 256] - bintotal[threadIdx.x + 256];
}

// Phase-1 scatter (dst): packed output (low9<<17 | src), cursors precomputed.
__global__ __launch_bounds__(256) void scatter_dst_kernel(
    const int* __restrict__ a_key, const int* __restrict__ f_key,
    const int* __restrict__ a_pay, const int* __restrict__ f_pay,
    int e_a, int E, const int* __restrict__ blkhist, int B,
    const int* __restrict__ binstart, int* __restrict__ opack) {
  __shared__ int cur[512];
  int b = blockIdx.x;
  for (int bin = threadIdx.x; bin < 512; bin += 256)
    cur[bin] = binstart[bin] + blkhist[bin * B + b];
  __syncthreads();
  int base = b * SORT_T;
  int end = base + SORT_T;
  if (end > E) end = E;
  for (int i = base + threadIdx.x; i < end; i += 256) {
    int k = edge_key(a_key, f_key, e_a, i);
    int pay = (i < e_a) ? a_pay[i] : f_pay[i - e_a];
    int pos = atomicAdd(&cur[k >> 9], 1);
    opack[pos] = ((k & 511) << 17) | pay;
  }
}

// Phase-1 scatter (src): u16 low-key only.
__global__ __launch_bounds__(256) void scatter_src_kernel(
    const int* __restrict__ a_key, const int* __restrict__ f_key,
    int e_a, int E, const int* __restrict__ blkhist, int B,
    const int* __restrict__ binstart, unsigned short* __restrict__ okey) {
  __shared__ int cur[512];
  int b = blockIdx.x;
  for (int bin = threadIdx.x; bin < 512; bin += 256)
    cur[bin] = binstart[bin] + blkhist[bin * B + b];
  __syncthreads();
  int base = b * SORT_T;
  int end = base + SORT_T;
  if (end > E) end = E;
  for (int i = base + threadIdx.x; i < end; i += 256) {
    int k = edge_key(a_key, f_key, e_a, i);
    int pos = atomicAdd(&cur[k >> 9], 1);
    okey[pos] = (unsigned short)(k & 511);
  }
}

// Phase-2 (dst): per-bucket LDS counting sort over low 9 bits. Writes csr
// (payload) at final positions and offs for the bucket's 512 node keys.
__global__ __launch_bounds__(256) void bucket_dst_kernel(
    const int* __restrict__ kp, const int* __restrict__ binstart, int E, int e_a,
    int* __restrict__ csr, int* __restrict__ offs_a, int n_a,
    int* __restrict__ offs_f, int n_f) {
  __shared__ int h[512], x[512], cur[512];
  int b = blockIdx.x;
  int s = binstart[b];
  int e = (b == 511) ? E : binstart[b + 1];
  for (int i = threadIdx.x; i < 512; i += 256) h[i] = 0;
  __syncthreads();
  for (int i = s + threadIdx.x; i < e; i += 256) atomicAdd(&h[kp[i] >> 17], 1);
  __syncthreads();
  for (int i = threadIdx.x; i < 512; i += 256) x[i] = h[i];
  __syncthreads();
  for (int o = 1; o < 512; o <<= 1) {
    int i0 = threadIdx.x, i1 = threadIdx.x + 256;
    int v0 = (i0 >= o) ? x[i0 - o] : 0;
    int v1 = (i1 >= o) ? x[i1 - o] : 0;
    __syncthreads();
    x[i0] += v0;
    x[i1] += v1;
    __syncthreads();
  }
  for (int low = threadIdx.x; low < 512; low += 256) {
    int gpos = s + x[low] - h[low];  // exclusive start of this key's run
    cur[low] = gpos;
    int key = (b << 9) | low;
    if (key < 65536) {
      if (key < n_a) offs_a[key] = gpos;
    } else {
      int v = key - 65536;
      if (v < n_f) offs_f[v] = gpos - e_a;
    }
  }
  __syncthreads();
  for (int i = s + threadIdx.x; i < e; i += 256) {
    int pv = kp[i];
    int pos = atomicAdd(&cur[pv >> 17], 1);
    csr[pos] = pv & 0x1FFFF;
  }
}

// Phase-2 (src): histogram + scan only -> offs_src (out-degree boundaries).
__global__ __launch_bounds__(256) void bucket_src_kernel(
    const unsigned short* __restrict__ kl, const int* __restrict__ binstart, int E, int e_a,
    int* __restrict__ offs_src_a, int n_a, int* __restrict__ offs_src_f, int n_f) {
  __shared__ int h[512], x[512];
  int b = blockIdx.x;
  int s = binstart[b];
  int e = (b == 511) ? E : binstart[b + 1];
  for (int i = threadIdx.x; i < 512; i += 256) h[i] = 0;
  __syncthreads();
  for (int i = s + threadIdx.x; i < e; i += 256) atomicAdd(&h[kl[i]], 1);
  __syncthreads();
  for (int i = threadIdx.x; i < 512; i += 256) x[i] = h[i];
  __syncthreads();
  for (int o = 1; o < 512; o <<= 1) {
    int i0 = threadIdx.x, i1 = threadIdx.x + 256;
    int v0 = (i0 >= o) ? x[i0 - o] : 0;
    int v1 = (i1 >= o) ? x[i1 - o] : 0;
    __syncthreads();
    x[i0] += v0;
    x[i1] += v1;
    __syncthreads();
  }
  for (int low = threadIdx.x; low < 512; low += 256) {
    int gpos = s + x[low] - h[low];
    int key = (b << 9) | low;
    if (key < 65536) {
      if (key < n_a) offs_src_a[key] = gpos;
    } else {
      int v = key - 65536;
      if (v < n_f) offs_src_f[v] = gpos - e_a;
    }
  }
}

// isr from offs diffs (needs sentinels).
__global__ void isr_kernel(const int* __restrict__ offs_a, const int* __restrict__ offs_src_a,
                           float* __restrict__ io_a, float* __restrict__ ii_a, int n_a,
                           const int* __restrict__ offs_f, const int* __restrict__ offs_src_f,
                           float* __restrict__ io_f, float* __restrict__ ii_f, int n_f) {
  int i = blockIdx.x * blockDim.x + threadIdx.x;
  if (i < n_a) {
    int ci = offs_a[i + 1] - offs_a[i];
    int co = offs_src_a[i + 1] - offs_src_a[i];
    ii_a[i] = 1.0f / sqrtf((float)(ci < 1 ? 1 : ci));
    io_a[i] = 1.0f / sqrtf((float)(co < 1 ? 1 : co));
  }
  if (i < n_f) {
    int ci = offs_f[i + 1] - offs_f[i];
    int co = offs_src_f[i + 1] - offs_src_f[i];
    ii_f[i] = 1.0f / sqrtf((float)(ci < 1 ? 1 : ci));
    io_f[i] = 1.0f / sqrtf((float)(co < 1 ? 1 : co));
  }
}

// ---------------------------------------------------------------------------
// LDS-free bf16-MFMA GEMM: C[M,N] = epi( (A[M,K](+s*add_vec[K])) @ B[K,N] )
// Bt is the pre-transposed bf16 [N][K] weight. Block = 4 waves x 16 rows
// (64 rows), each wave computes its 16 rows x full N. A-fragments are
// wave-private -> loaded directly from global as bf16x8 (or 2x float4 + cvt
// for fp32 input); B-fragments load directly from Bt (L1/L2-hot, shared by
// every block). No LDS, no barriers; K/32 loop fully unrolled via template.
// epi: *rowscale[M]? +bias[N]? out bf16 or fp32.
// ---------------------------------------------------------------------------
template <int K, int N>
__global__ __launch_bounds__(256) void gemm_direct_kernel(
    const void* __restrict__ A, const unsigned short* __restrict__ Bt,
    void* __restrict__ C, int M,
    const float* __restrict__ add_vec, float add_scale,
    const float* __restrict__ rowscale, const float* __restrict__ bias,
    int in_bf16, int out_bf16) {
  const int tid = threadIdx.x;
  const int lane = tid & 63, w = tid >> 6;
  const int q = lane >> 4, l16 = lane & 15;
  const int m0 = blockIdx.x * 64;
  const int m = m0 + w * 16 + l16;
  const int mload = (m < M) ? m : (M - 1);  // clamp; stores are guarded
  constexpr int NT = N / 16;
  f32x4 acc[NT] = {};
#pragma unroll
  for (int kk = 0; kk < K / 32; ++kk) {
    const int kb = kk * 32 + q * 8;
    bf16x8 af;
    if (in_bf16) {
      af = *reinterpret_cast<const bf16x8*>((const unsigned short*)A + (size_t)mload * K + kb);
      if (add_vec) {
        float4 av0 = *reinterpret_cast<const float4*>(add_vec + kb);
        float4 av1 = *reinterpret_cast<const float4*>(add_vec + kb + 4);
        u16x8 u = (u16x8)af;
        bf16x8 t;
        t[0] = (short)f2bf(bf2f(u[0]) + add_scale * av0.x);
        t[1] = (short)f2bf(bf2f(u[1]) + add_scale * av0.y);
        t[2] = (short)f2bf(bf2f(u[2]) + add_scale * av0.z);
        t[3] = (short)f2bf(bf2f(u[3]) + add_scale * av0.w);
        t[4] = (short)f2bf(bf2f(u[4]) + add_scale * av1.x);
        t[5] = (short)f2bf(bf2f(u[5]) + add_scale * av1.y);
        t[6] = (short)f2bf(bf2f(u[6]) + add_scale * av1.z);
        t[7] = (short)f2bf(bf2f(u[7]) + add_scale * av1.w);
        af = t;
      }
    } else {
      const float* s = (const float*)A + (size_t)mload * K + kb;
      float4 v0 = *reinterpret_cast<const float4*>(s);
      float4 v1 = *reinterpret_cast<const float4*>(s + 4);
      bf16x8 t;
      t[0] = (short)f2bf(v0.x); t[1] = (short)f2bf(v0.y);
      t[2] = (short)f2bf(v0.z); t[3] = (short)f2bf(v0.w);
      t[4] = (short)f2bf(v1.x); t[5] = (short)f2bf(v1.y);
      t[6] = (short)f2bf(v1.z); t[7] = (short)f2bf(v1.w);
      af = t;
    }
#pragma unroll
    for (int nt = 0; nt < NT; ++nt) {
      bf16x8 bf =
          *reinterpret_cast<const bf16x8*>(Bt + (size_t)(nt * 16 + l16) * K + kb);
      acc[nt] = __builtin_amdgcn_mfma_f32_16x16x32_bf16(af, bf, acc[nt], 0, 0, 0);
    }
  }
#pragma unroll
  for (int nt = 0; nt < NT; ++nt) {
    int gcol = nt * 16 + l16;
    float bv = bias ? bias[gcol] : 0.f;
#pragma unroll
    for (int r = 0; r < 4; ++r) {
      int grow = m0 + w * 16 + q * 4 + r;
      if (grow < M) {
        float v = acc[nt][r];
        if (rowscale) v *= rowscale[grow];
        v += bv;
        if (out_bf16)
          ((unsigned short*)C)[(size_t)grow * N + gcol] = f2bf(v);
        else
          ((float*)C)[(size_t)grow * N + gcol] = v;
      }
    }
  }
}

// h[node] = relu( (sum_{e in CSR[node]} XW_bf16[src(e)]) * isr_in[node] + b )
// 32 threads per node, 8 nodes/block, 4-wide unroll (4 row loads in flight).
// mode 0: write h rows bf16 to out[node*128..].
// mode 1: per-block channel SUMS  -> out[blockIdx*128..] (fp32 partials).
// mode 2: per-block channel MAXES -> out[blockIdx*128..] (fp32, h>=0).
__global__ __launch_bounds__(256) void agg_kernel(
    const unsigned short* __restrict__ XW, const int* __restrict__ offs,
    const int* __restrict__ csr, const float* __restrict__ isr_in,
    const float* __restrict__ bias, void* __restrict__ out, int n, int mode) {
  __shared__ float red[8][128];
  int lane = threadIdx.x & 31;
  int g = threadIdx.x >> 5;
  int node = blockIdx.x * 8 + g;
  float4 o = make_float4(0.f, 0.f, 0.f, 0.f);
  if (node < n) {
    int e0 = offs[node], e1 = offs[node + 1];
    float4 a0 = make_float4(0.f, 0.f, 0.f, 0.f);
    float4 a1 = a0, a2 = a0, a3 = a0;
    int e = e0;
    for (; e + 4 <= e1; e += 4) {
      int s0 = csr[e], s1 = csr[e + 1], s2 = csr[e + 2], s3 = csr[e + 3];
      ushort4 v0 = *reinterpret_cast<const ushort4*>(&XW[(size_t)s0 * 128 + lane * 4]);
      ushort4 v1 = *reinterpret_cast<const ushort4*>(&XW[(size_t)s1 * 128 + lane * 4]);
      ushort4 v2 = *reinterpret_cast<const ushort4*>(&XW[(size_t)s2 * 128 + lane * 4]);
      ushort4 v3 = *reinterpret_cast<const ushort4*>(&XW[(size_t)s3 * 128 + lane * 4]);
      a0.x += bf2f(v0.x); a0.y += bf2f(v0.y); a0.z += bf2f(v0.z); a0.w += bf2f(v0.w);
      a1.x += bf2f(v1.x); a1.y += bf2f(v1.y); a1.z += bf2f(v1.z); a1.w += bf2f(v1.w);
      a2.x += bf2f(v2.x); a2.y += bf2f(v2.y); a2.z += bf2f(v2.z); a2.w += bf2f(v2.w);
      a3.x += bf2f(v3.x); a3.y += bf2f(v3.y); a3.z += bf2f(v3.z); a3.w += bf2f(v3.w);
    }
    for (; e < e1; ++e) {
      int s = csr[e];
      ushort4 v = *reinterpret_cast<const ushort4*>(&XW[(size_t)s * 128 + lane * 4]);
      a0.x += bf2f(v.x); a0.y += bf2f(v.y); a0.z += bf2f(v.z); a0.w += bf2f(v.w);
    }
    float4 acc;
    acc.x = (a0.x + a1.x) + (a2.x + a3.x);
    acc.y = (a0.y + a1.y) + (a2.y + a3.y);
    acc.z = (a0.z + a1.z) + (a2.z + a3.z);
    acc.w = (a0.w + a1.w) + (a2.w + a3.w);
    float sc = isr_in[node];
    float4 b = *reinterpret_cast<const float4*>(&bias[lane * 4]);
    o.x = fmaxf(fmaf(acc.x, sc, b.x), 0.f);
    o.y = fmaxf(fmaf(acc.y, sc, b.y), 0.f);
    o.z = fmaxf(fmaf(acc.z, sc, b.z), 0.f);
    o.w = fmaxf(fmaf(acc.w, sc, b.w), 0.f);
  }
  if (mode == 0) {
    if (node < n) {
      ushort4 st;
      st.x = f2bf(o.x); st.y = f2bf(o.y); st.z = f2bf(o.z); st.w = f2bf(o.w);
      *reinterpret_cast<ushort4*>(&((unsigned short*)out)[(size_t)node * 128 + lane * 4]) = st;
    }
    return;
  }
  // Reduce modes: zeros from padded nodes are identity for sum and for max
  // (h >= 0 after relu).
  red[g][lane * 4 + 0] = o.x;
  red[g][lane * 4 + 1] = o.y;
  red[g][lane * 4 + 2] = o.z;
  red[g][lane * 4 + 3] = o.w;
  __syncthreads();
  if (threadIdx.x < 128) {
    float v = red[0][threadIdx.x];
    if (mode == 1) {
#pragma unroll
      for (int j = 1; j < 8; ++j) v += red[j][threadIdx.x];
    } else {
#pragma unroll
      for (int j = 1; j < 8; ++j) v = fmaxf(v, red[j][threadIdx.x]);
    }
    ((float*)out)[(size_t)blockIdx.x * 128 + threadIdx.x] = v;
  }
}

// out[col] += column sums of X[n, ncol] (fp32 or bf16); out pre-zeroed.
__global__ __launch_bounds__(256) void colsum_kernel(const void* __restrict__ X,
                                                     float* __restrict__ out, int n, int ncol,
                                                     int xbf16) {
  __shared__ float s[256];
  int col = threadIdx.x % ncol;
  int rpb = 256 / ncol;
  int rb = threadIdx.x / ncol;
  float acc = 0.f;
  for (int r = blockIdx.x * rpb + rb; r < n; r += gridDim.x * rpb) {
    size_t idx = (size_t)r * ncol + col;
    acc += xbf16 ? bf2f(((const unsigned short*)X)[idx]) : ((const float*)X)[idx];
  }
  s[threadIdx.x] = acc;
  __syncthreads();
  if (threadIdx.x < ncol) {
    float v = 0.f;
    for (int i = 0; i < rpb; ++i) v += s[threadIdx.x + i * ncol];
    atomicAdd(&out[col], v);
  }
}

// out[col] = max over rows (X >= 0; out pre-zeroed). Bit-compare trick.
__global__ __launch_bounds__(256) void colmax_kernel(const float* __restrict__ X,
                                                     unsigned* __restrict__ out, int n, int ncol) {
  __shared__ float s[256];
  int col = threadIdx.x % ncol;
  int rpb = 256 / ncol;
  int rb = threadIdx.x / ncol;
  float acc = 0.f;
  for (int r = blockIdx.x * rpb + rb; r < n; r += gridDim.x * rpb)
    acc = fmaxf(acc, X[(size_t)r * ncol + col]);
  s[threadIdx.x] = acc;
  __syncthreads();
  if (threadIdx.x < ncol) {
    float v = s[threadIdx.x];
    for (int i = 1; i < rpb; ++i) v = fmaxf(v, s[threadIdx.x + i * ncol]);
    atomicMax(&out[col], __float_as_uint(v));
  }
}

// norm_embed(a) + norm_embed(f) then @ W_cls + b_cls. Single block of 128.
__global__ __launch_bounds__(128) void final_kernel(
    const float* __restrict__ emb_a_sum, const unsigned* __restrict__ emb_f_bits,
    const float* __restrict__ W_cls, const float* __restrict__ b_cls,
    float* __restrict__ out, float inv_n_apig, int ncls) {
  __shared__ float red[128];
  __shared__ float emb[128];
  int t = threadIdx.x;
  float a = emb_a_sum[t] * inv_n_apig;
  float f = __uint_as_float(emb_f_bits[t]);

  float vals[2] = {a, f};
  float norms[2];
#pragma unroll
  for (int which = 0; which < 2; ++which) {
    float x = vals[which];
    red[t] = x;
    __syncthreads();
    for (int o = 64; o > 0; o >>= 1) {
      if (t < o) red[t] += red[t + o];
      __syncthreads();
    }
    float mean = red[0] / 128.f;
    __syncthreads();
    float d = x - mean;
    red[t] = d * d;
    __syncthreads();
    for (int o = 64; o > 0; o >>= 1) {
      if (t < o) red[t] += red[t + o];
      __syncthreads();
    }
    float stdv = sqrtf(red[0] / 127.f);  // ddof=1
    __syncthreads();
    float z = d / stdv;
    red[t] = z;
    __syncthreads();
    for (int o = 64; o > 0; o >>= 1) {
      if (t < o) red[t] = fminf(red[t], red[t + o]);
      __syncthreads();
    }
    float zmin = red[0];
    __syncthreads();
    red[t] = z;
    __syncthreads();
    for (int o = 64; o > 0; o >>= 1) {
      if (t < o) red[t] = fmaxf(red[t], red[t + o]);
      __syncthreads();
    }
    float zmax = red[0];
    __syncthreads();
    norms[which] = (z - zmin) / (zmax - zmin);
  }

  emb[t] = norms[0] + norms[1];
  __syncthreads();
  if (t < ncls) {
    float acc = b_cls[t];
    for (int k = 0; k < 128; ++k) acc = fmaf(emb[k], W_cls[k * ncls + t], acc);
    out[t] = acc;
  }
}

extern "C" void kernel_launch(void* const* d_in, const int* in_sizes, int n_in,
                              void* d_out, int out_size, void* d_ws, size_t ws_size,
                              hipStream_t stream) {
  const float* apig_feat = (const float*)d_in[0];
  const float* fcg_feat = (const float*)d_in[1];
  const float* W_a1 = (const float*)d_in[2];
  const float* b_a1 = (const float*)d_in[3];
  const float* W_a2 = (const float*)d_in[4];
  const float* b_a2 = (const float*)d_in[5];
  const float* W_f1 = (const float*)d_in[6];
  const float* b_f1 = (const float*)d_in[7];
  const float* W_f2 = (const float*)d_in[8];
  const float* b_f2 = (const float*)d_in[9];
  const float* W1 = (const float*)d_in[10];
  const float* b1 = (const float*)d_in[11];
  const float* W2 = (const float*)d_in[12];
  const float* b2 = (const float*)d_in[13];
  // d_in[14]/d_in[15] (W_attn, b_attn): dead — softmax over length-1 axis == 1.
  const float* W_cls = (const float*)d_in[16];
  const float* b_cls = (const float*)d_in[17];
  const int* a_src = (const int*)d_in[18];
  const int* a_dst = (const int*)d_in[19];
  const int* f_src = (const int*)d_in[20];
  const int* f_dst = (const int*)d_in[21];

  const int hidden = in_sizes[3];             // 128
  const int united = in_sizes[11];            // 64
  const int ncls = in_sizes[17];              // 10
  const int apig_dim = in_sizes[2] / hidden;  // 256
  const int fcg_dim = in_sizes[6] / hidden;   // 128
  const int n_a = in_sizes[0] / apig_dim;     // 50000
  const int n_f = in_sizes[1] / fcg_dim;      // 100000
  const int e_a = in_sizes[18];               // 800000
  const int e_f = in_sizes[20];               // 1600000

  // ---- workspace carve-up (all 256B aligned) ----
  char* w = (char*)d_ws;
  auto alloc = [&](size_t bytes) -> void* {
    void* p = (void*)w;
    w += (bytes + 255) & ~(size_t)255;
    return p;
  };
  const int E_tot = e_a + e_f;
  const int B = (E_tot + SORT_T - 1) / SORT_T;
  const int nblkA = (n_a + 7) / 8, nblkF = (n_f + 7) / 8;

  float* isr_out_a = (float*)alloc((size_t)n_a * 4);
  float* isr_in_a = (float*)alloc((size_t)n_a * 4);
  float* isr_out_f = (float*)alloc((size_t)n_f * 4);
  float* isr_in_f = (float*)alloc((size_t)n_f * 4);
  int* offs_a = (int*)alloc((size_t)(n_a + 1) * 4);
  int* offs_f = (int*)alloc((size_t)(n_f + 1) * 4);
  int* offs_src_a = (int*)alloc((size_t)(n_a + 1) * 4);
  int* offs_src_f = (int*)alloc((size_t)(n_f + 1) * 4);
  int* kp = (int*)alloc((size_t)E_tot * 4);   // packed dst-sort output; u16 src reuses
  int* csr = (int*)alloc((size_t)E_tot * 4);  // final CSR (apig [0,e_a), fcg [e_a,..))
  int* blkhist = (int*)alloc((size_t)512 * B * 4);
  int* bintotal = (int*)alloc((size_t)512 * 4);
  int* binstart = (int*)alloc((size_t)512 * 4);
  unsigned short* G_a = (unsigned short*)alloc((size_t)n_a * hidden * 2);  // bf16 table
  unsigned short* H_a = (unsigned short*)alloc((size_t)n_a * hidden * 2);  // h1 / a_dec (bf16)
  unsigned short* G_f = (unsigned short*)alloc((size_t)n_f * hidden * 2);
  unsigned short* H_f = (unsigned short*)alloc((size_t)n_f * hidden * 2);
  float* P = (float*)alloc((size_t)nblkF * hidden * 4);  // conv2 block partials
  unsigned short* E_a = G_a;  // enc raw (bf16, n x 64) aliases G_a (disjoint lifetimes)
  unsigned short* E_f = G_f;
  float* a_sum = (float*)alloc((size_t)united * 4);
  float* f_sum = (float*)alloc((size_t)united * 4);
  float* emb_a = (float*)alloc((size_t)hidden * 4);
  unsigned* emb_f = (unsigned*)alloc((size_t)hidden * 4);
  // bf16 [N][K] pre-transposed weights
  unsigned short* T_a1 = (unsigned short*)alloc((size_t)apig_dim * hidden * 2);
  unsigned short* T_f1 = (unsigned short*)alloc((size_t)fcg_dim * hidden * 2);
  unsigned short* T_a2 = (unsigned short*)alloc((size_t)hidden * hidden * 2);
  unsigned short* T_f2 = (unsigned short*)alloc((size_t)hidden * hidden * 2);
  unsigned short* T1 = (unsigned short*)alloc((size_t)hidden * united * 2);
  unsigned short* T2 = (unsigned short*)alloc((size_t)united * hidden * 2);
  int* csr_a = csr;
  int* csr_f = csr + e_a;
  unsigned short* ks = (unsigned short*)kp;  // src-sort u16 keys (after dst sort done)
  (void)ws_size;
  (void)n_in;
  (void)out_size;

  dim3 blk(256);

  // ---- init tiny accumulators + offs sentinels; weight transpose prep ----
  zero_small_kernel<<<1, 128, 0, stream>>>(a_sum, f_sum, united, emb_a, emb_f, hidden,
                                           offs_a, offs_src_a, n_a, e_a,
                                           offs_f, offs_src_f, n_f, e_f);
  prep_bt_kernel<<<dim3(32, 6), blk, 0, stream>>>(W_a1, W_f1, W_a2, W_f2, W1, W2,
                                                  T_a1, T_f1, T_a2, T_f2, T1, T2);

  // ---- CSR build: dst sort (hist -> cursor -> binscan -> scatter -> bucket) ----
  radix_hist_kernel<<<B, blk, 0, stream>>>(a_dst, f_dst, e_a, E_tot, blkhist, B);
  cursor_kernel<<<512, blk, 0, stream>>>(blkhist, B, bintotal);
  binscan_kernel<<<1, blk, 0, stream>>>(bintotal, binstart);
  scatter_dst_kernel<<<B, blk, 0, stream>>>(a_dst, f_dst, a_src, f_src, e_a, E_tot,
                                            blkhist, B, binstart, kp);
  bucket_dst_kernel<<<512, blk, 0, stream>>>(kp, binstart, E_tot, e_a,
                                             csr, offs_a, n_a, offs_f, n_f);
  // ---- src sort (keys only) -> offs_src (out-degrees) ----
  radix_hist_kernel<<<B, blk, 0, stream>>>(a_src, f_src, e_a, E_tot, blkhist, B);
  cursor_kernel<<<512, blk, 0, stream>>>(blkhist, B, bintotal);
  binscan_kernel<<<1, blk, 0, stream>>>(bintotal, binstart);
  scatter_src_kernel<<<B, blk, 0, stream>>>(a_src, f_src, e_a, E_tot, blkhist, B,
                                            binstart, ks);
  bucket_src_kernel<<<512, blk, 0, stream>>>(ks, binstart, E_tot, e_a,
                                             offs_src_a, n_a, offs_src_f, n_f);
  isr_kernel<<<(n_f + 255) / 256, blk, 0, stream>>>(offs_a, offs_src_a, isr_out_a, isr_in_a,
                                                    n_a, offs_f, offs_src_f, isr_out_f,
                                                    isr_in_f, n_f);

  const int ga = (n_a + 63) / 64, gf = (n_f + 63) / 64;

  // ---- apig conv1 + enc ----
  gemm_direct_kernel<256, 128><<<ga, blk, 0, stream>>>(
      apig_feat, T_a1, G_a, n_a, nullptr, 0.f, isr_out_a, nullptr, 0, 1);
  agg_kernel<<<nblkA, blk, 0, stream>>>(G_a, offs_a, csr_a, isr_in_a, b_a1, H_a, n_a, 0);
  gemm_direct_kernel<128, 64><<<ga, blk, 0, stream>>>(
      H_a, T1, E_a, n_a, nullptr, 0.f, nullptr, b1, 1, 1);  // E_a=G_a (dead)
  colsum_kernel<<<256, blk, 0, stream>>>(E_a, a_sum, n_a, united, 1);

  // ---- fcg conv1 + enc ----
  gemm_direct_kernel<128, 128><<<gf, blk, 0, stream>>>(
      fcg_feat, T_f1, G_f, n_f, nullptr, 0.f, isr_out_f, nullptr, 0, 1);
  agg_kernel<<<nblkF, blk, 0, stream>>>(G_f, offs_f, csr_f, isr_in_f, b_f1, H_f, n_f, 0);
  gemm_direct_kernel<128, 64><<<gf, blk, 0, stream>>>(
      H_f, T1, E_f, n_f, nullptr, 0.f, nullptr, b1, 1, 1);
  colsum_kernel<<<256, blk, 0, stream>>>(E_f, f_sum, n_f, united, 1);

  // ---- apig dec + conv2 + mean (H2 never materialized) ----
  gemm_direct_kernel<64, 128><<<ga, blk, 0, stream>>>(
      E_a, T2, H_a, n_a, f_sum, 0.1f, nullptr, b2, 1, 1);  // a_dec -> H_a
  gemm_direct_kernel<128, 128><<<ga, blk, 0, stream>>>(
      H_a, T_a2, G_a, n_a, nullptr, 0.f, isr_out_a, nullptr, 1, 1);
  agg_kernel<<<nblkA, blk, 0, stream>>>(G_a, offs_a, csr_a, isr_in_a, b_a2, P, n_a, 1);
  colsum_kernel<<<256, blk, 0, stream>>>(P, emb_a, nblkA, hidden, 0);

  // ---- fcg dec + conv2 + max ----
  gemm_direct_kernel<64, 128><<<gf, blk, 0, stream>>>(
      E_f, T2, H_f, n_f, a_sum, 0.1f, nullptr, b2, 1, 1);  // f_dec -> H_f
  gemm_direct_kernel<128, 128><<<gf, blk, 0, stream>>>(
      H_f, T_f2, G_f, n_f, nullptr, 0.f, isr_out_f, nullptr, 1, 1);
  agg_kernel<<<nblkF, blk, 0, stream>>>(G_f, offs_f, csr_f, isr_in_f, b_f2, P, n_f, 2);
  colmax_kernel<<<256, blk, 0, stream>>>(P, emb_f, nblkF, hidden);

  // ---- head ----
  final_kernel<<<1, 128, 0, stream>>>(emb_a, emb_f, W_cls, b_cls, (float*)d_out,
                                      1.0f / (float)n_a, ncls);
}

// Round 2
// 663.268 us; speedup vs baseline: 1.2154x; 1.2154x over previous
//
#include <hip/hip_runtime.h>
#include <math.h>

// ---------------------------------------------------------------------------
// MultiGraphClassifier on MI355X.
// Pipeline: 2x GraphConv per graph + cross-graph fusion + tiny head.
// Strategy: ATOMIC-FREE CSR build via MSD radix bucketing + per-bucket LDS
// counting sort; gather-side aggregation over bf16 tables; bf16-MFMA GEMMs
// with fp32 accumulate and fused epilogues. All node intermediates
// (G,H,E,dec) bf16. conv2's H is never materialized: agg reduces per-block
// channel partials (sum/max) into a small P matrix, reduced by colsum/colmax.
// Note: softmax over a length-1 axis == 1.0, so emb = norm(a) + norm(f).
// R1: 3-phase scan. R3: atomic-free scatter. R4: bf16 MFMA + bf16 tables.
// R5: 4-wide agg unroll. R6/R7 FALSIFIED: global-atomic scope/sharding is
//   irrelevant — fixed ~21G/s memory-side RMW ceiling. R8: radix sort (no
//   global atomics). R9: SORT_T=4096 + decoupled cursor scan (786us).
// R10: bf16 intermediates + fused conv2 reductions (~345MB traffic removed).
// R11 FALSIFIED: fully LDS-free GEMM is LATENCY-BOUND (MfmaUtil 1.7%,
//   VALUBusy 8%, occ 30%, 750 GB/s) — VGPR=52 meant ~2 loads in flight and
//   the MFMA chain stalled on global latency. LDS staging is what decouples
//   global latency from the MFMA chain, not a reuse optimization here.
// R12: hybrid GEMM. B (pre-transposed bf16 [N][K], 16-35KB) staged to LDS
//   cooperatively with +16B row pad (conflict-free ds_read_b128); A fragments
//   are wave-private -> per-lane direct global loads ALL ISSUED FIRST so
//   their latency hides under B staging + barrier; MFMA operands SWAPPED
//   (mfma(bf,af) = C^T tile) so each lane owns one row x 4 consecutive cols:
//   epilogue = 8x 8B stores (was 32x 2B) and scalar rowscale. K=256 runs as
//   two 128-wide stages (static LDS <= 64KB). K,N,dtype templated.
// ---------------------------------------------------------------------------

typedef __attribute__((ext_vector_type(8))) short bf16x8;
typedef __attribute__((ext_vector_type(8))) unsigned short u16x8;
typedef __attribute__((ext_vector_type(4))) float f32x4;

#define SORT_T 4096  // edges per phase-1 block

static __device__ inline unsigned short f2bf(float f) {
  unsigned u = __float_as_uint(f);
  unsigned r = (u + 0x7fff + ((u >> 16) & 1)) >> 16;  // RNE
  return (unsigned short)r;
}
static __device__ inline float bf2f(unsigned short h) {
  return __uint_as_float(((unsigned)h) << 16);
}

// Zero tiny accumulators + write offs sentinels. One block of 128.
__global__ void zero_small_kernel(float* __restrict__ s0, float* __restrict__ s1, int ns,
                                  float* __restrict__ ea, unsigned* __restrict__ ef, int ne,
                                  int* __restrict__ offs_a, int* __restrict__ offs_src_a,
                                  int n_a, int e_a,
                                  int* __restrict__ offs_f, int* __restrict__ offs_src_f,
                                  int n_f, int e_f) {
  int i = threadIdx.x;
  if (i < ns) { s0[i] = 0.f; s1[i] = 0.f; }
  if (i < ne) { ea[i] = 0.f; ef[i] = 0u; }
  if (i == 0) {
    offs_a[n_a] = e_a;
    offs_src_a[n_a] = e_a;
    offs_f[n_f] = e_f;
    offs_src_f[n_f] = e_f;
  }
}

// One-time weight prep: Bt[n*K + k] = bf16(W[k*N + n]) for the 6 GEMM weights.
__global__ __launch_bounds__(256) void prep_bt_kernel(
    const float* __restrict__ W_a1, const float* __restrict__ W_f1,
    const float* __restrict__ W_a2, const float* __restrict__ W_f2,
    const float* __restrict__ W1, const float* __restrict__ W2,
    unsigned short* __restrict__ T_a1, unsigned short* __restrict__ T_f1,
    unsigned short* __restrict__ T_a2, unsigned short* __restrict__ T_f2,
    unsigned short* __restrict__ T1, unsigned short* __restrict__ T2) {
  const float* src;
  unsigned short* dst;
  int K, N;
  switch (blockIdx.y) {
    case 0: src = W_a1; dst = T_a1; K = 256; N = 128; break;
    case 1: src = W_f1; dst = T_f1; K = 128; N = 128; break;
    case 2: src = W_a2; dst = T_a2; K = 128; N = 128; break;
    case 3: src = W_f2; dst = T_f2; K = 128; N = 128; break;
    case 4: src = W1;   dst = T1;   K = 128; N = 64;  break;
    default: src = W2;  dst = T2;   K = 64;  N = 128; break;
  }
  int total = K * N;
  for (int idx = blockIdx.x * 256 + threadIdx.x; idx < total; idx += gridDim.x * 256) {
    int n = idx / K, k = idx - n * K;
    dst[idx] = f2bf(src[(size_t)k * N + n]);
  }
}

// Combined key at edge i: apig -> key, fcg -> key + 65536 (18-bit space).
static __device__ inline int edge_key(const int* __restrict__ a_key,
                                      const int* __restrict__ f_key, int e_a, int i) {
  return (i < e_a) ? a_key[i] : (f_key[i - e_a] + 65536);
}

// Phase-1 histogram over high 9 bits. LDS atomics only.
__global__ __launch_bounds__(256) void radix_hist_kernel(
    const int* __restrict__ a_key, const int* __restrict__ f_key, int e_a, int E,
    int* __restrict__ blkhist, int B) {
  __shared__ int h[512];
  for (int i = threadIdx.x; i < 512; i += 256) h[i] = 0;
  __syncthreads();
  int base = blockIdx.x * SORT_T;
  int end = base + SORT_T;
  if (end > E) end = E;
  for (int i = base + threadIdx.x; i < end; i += 256)
    atomicAdd(&h[edge_key(a_key, f_key, e_a, i) >> 9], 1);
  __syncthreads();
  for (int i = threadIdx.x; i < 512; i += 256) blkhist[i * B + blockIdx.x] = h[i];
}

// One block per bin: exclusive prefix over the bin's B block-counts (in
// place) + bin total.
__global__ __launch_bounds__(256) void cursor_kernel(int* __restrict__ blkhist, int B,
                                                     int* __restrict__ bintotal) {
  __shared__ int part[256];
  int* row = blkhist + (size_t)blockIdx.x * B;
  int C = (B + 255) / 256;
  int start = threadIdx.x * C;
  int end = start + C;
  if (end > B) end = B;
  int v[8];  // C <= 8 for B <= 2048
  int s = 0;
  for (int j = start; j < end; ++j) {
    v[j - start] = row[j];
    s += v[j - start];
  }
  part[threadIdx.x] = s;
  __syncthreads();
  for (int o = 1; o < 256; o <<= 1) {
    int u = (threadIdx.x >= o) ? part[threadIdx.x - o] : 0;
    __syncthreads();
    part[threadIdx.x] += u;
    __syncthreads();
  }
  int run = part[threadIdx.x] - s;  // exclusive
  for (int j = start; j < end; ++j) {
    row[j] = run;
    run += v[j - start];
  }
  if (threadIdx.x == 255) bintotal[blockIdx.x] = part[255];
}

// Exclusive scan of 512 bin totals -> binstart. One block of 256.
__global__ __launch_bounds__(256) void binscan_kernel(const int* __restrict__ bintotal,
                                                      int* __restrict__ binstart) {
  __shared__ int x[512];
  x[threadIdx.x] = bintotal[threadIdx.x];
  x[threadIdx.x + 256] = bintotal[threadIdx.x + 256];
  __syncthreads();
  for (int o = 1; o < 512; o <<= 1) {
    int i0 = threadIdx.x, i1 = threadIdx.x + 256;
    int v0 = (i0 >= o) ? x[i0 - o] : 0;
    int v1 = (i1 >= o) ? x[i1 - o] : 0;
    __syncthreads();
    x[i0] += v0;
    x[i1] += v1;
    __syncthreads();
  }
  binstart[threadIdx.x] = x[threadIdx.x] - bintotal[threadIdx.x];
  binstart[threadIdx.x + 256] = x[threadIdx.x + 256] - bintotal[threadIdx.x + 256];
}

// Phase-1 scatter (dst): packed output (low9<<17 | src), cursors precomputed.
__global__ __launch_bounds__(256) void scatter_dst_kernel(
    const int* __restrict__ a_key, const int* __restrict__ f_key,
    const int* __restrict__ a_pay, const int* __restrict__ f_pay,
    int e_a, int E, const int* __restrict__ blkhist, int B,
    const int* __restrict__ binstart, int* __restrict__ opack) {
  __shared__ int cur[512];
  int b = blockIdx.x;
  for (int bin = threadIdx.x; bin < 512; bin += 256)
    cur[bin] = binstart[bin] + blkhist[bin * B + b];
  __syncthreads();
  int base = b * SORT_T;
  int end = base + SORT_T;
  if (end > E) end = E;
  for (int i = base + threadIdx.x; i < end; i += 256) {
    int k = edge_key(a_key, f_key, e_a, i);
    int pay = (i < e_a) ? a_pay[i] : f_pay[i - e_a];
    int pos = atomicAdd(&cur[k >> 9], 1);
    opack[pos] = ((k & 511) << 17) | pay;
  }
}

// Phase-1 scatter (src): u16 low-key only.
__global__ __launch_bounds__(256) void scatter_src_kernel(
    const int* __restrict__ a_key, const int* __restrict__ f_key,
    int e_a, int E, const int* __restrict__ blkhist, int B,
    const int* __restrict__ binstart, unsigned short* __restrict__ okey) {
  __shared__ int cur[512];
  int b = blockIdx.x;
  for (int bin = threadIdx.x; bin < 512; bin += 256)
    cur[bin] = binstart[bin] + blkhist[bin * B + b];
  __syncthreads();
  int base = b * SORT_T;
  int end = base + SORT_T;
  if (end > E) end = E;
  for (int i = base + threadIdx.x; i < end; i += 256) {
    int k = edge_key(a_key, f_key, e_a, i);
    int pos = atomicAdd(&cur[k >> 9], 1);
    okey[pos] = (unsigned short)(k & 511);
  }
}

// Phase-2 (dst): per-bucket LDS counting sort over low 9 bits. Writes csr
// (payload) at final positions and offs for the bucket's 512 node keys.
__global__ __launch_bounds__(256) void bucket_dst_kernel(
    const int* __restrict__ kp, const int* __restrict__ binstart, int E, int e_a,
    int* __restrict__ csr, int* __restrict__ offs_a, int n_a,
    int* __restrict__ offs_f, int n_f) {
  __shared__ int h[512], x[512], cur[512];
  int b = blockIdx.x;
  int s = binstart[b];
  int e = (b == 511) ? E : binstart[b + 1];
  for (int i = threadIdx.x; i < 512; i += 256) h[i] = 0;
  __syncthreads();
  for (int i = s + threadIdx.x; i < e; i += 256) atomicAdd(&h[kp[i] >> 17], 1);
  __syncthreads();
  for (int i = threadIdx.x; i < 512; i += 256) x[i] = h[i];
  __syncthreads();
  for (int o = 1; o < 512; o <<= 1) {
    int i0 = threadIdx.x, i1 = threadIdx.x + 256;
    int v0 = (i0 >= o) ? x[i0 - o] : 0;
    int v1 = (i1 >= o) ? x[i1 - o] : 0;
    __syncthreads();
    x[i0] += v0;
    x[i1] += v1;
    __syncthreads();
  }
  for (int low = threadIdx.x; low < 512; low += 256) {
    int gpos = s + x[low] - h[low];  // exclusive start of this key's run
    cur[low] = gpos;
    int key = (b << 9) | low;
    if (key < 65536) {
      if (key < n_a) offs_a[key] = gpos;
    } else {
      int v = key - 65536;
      if (v < n_f) offs_f[v] = gpos - e_a;
    }
  }
  __syncthreads();
  for (int i = s + threadIdx.x; i < e; i += 256) {
    int pv = kp[i];
    int pos = atomicAdd(&cur[pv >> 17], 1);
    csr[pos] = pv & 0x1FFFF;
  }
}

// Phase-2 (src): histogram + scan only -> offs_src (out-degree boundaries).
__global__ __launch_bounds__(256) void bucket_src_kernel(
    const unsigned short* __restrict__ kl, const int* __restrict__ binstart, int E, int e_a,
    int* __restrict__ offs_src_a, int n_a, int* __restrict__ offs_src_f, int n_f) {
  __shared__ int h[512], x[512];
  int b = blockIdx.x;
  int s = binstart[b];
  int e = (b == 511) ? E : binstart[b + 1];
  for (int i = threadIdx.x; i < 512; i += 256) h[i] = 0;
  __syncthreads();
  for (int i = s + threadIdx.x; i < e; i += 256) atomicAdd(&h[kl[i]], 1);
  __syncthreads();
  for (int i = threadIdx.x; i < 512; i += 256) x[i] = h[i];
  __syncthreads();
  for (int o = 1; o < 512; o <<= 1) {
    int i0 = threadIdx.x, i1 = threadIdx.x + 256;
    int v0 = (i0 >= o) ? x[i0 - o] : 0;
    int v1 = (i1 >= o) ? x[i1 - o] : 0;
    __syncthreads();
    x[i0] += v0;
    x[i1] += v1;
    __syncthreads();
  }
  for (int low = threadIdx.x; low < 512; low += 256) {
    int gpos = s + x[low] - h[low];
    int key = (b << 9) | low;
    if (key < 65536) {
      if (key < n_a) offs_src_a[key] = gpos;
    } else {
      int v = key - 65536;
      if (v < n_f) offs_src_f[v] = gpos - e_a;
    }
  }
}

// isr from offs diffs (needs sentinels).
__global__ void isr_kernel(const int* __restrict__ offs_a, const int* __restrict__ offs_src_a,
                           float* __restrict__ io_a, float* __restrict__ ii_a, int n_a,
                           const int* __restrict__ offs_f, const int* __restrict__ offs_src_f,
                           float* __restrict__ io_f, float* __restrict__ ii_f, int n_f) {
  int i = blockIdx.x * blockDim.x + threadIdx.x;
  if (i < n_a) {
    int ci = offs_a[i + 1] - offs_a[i];
    int co = offs_src_a[i + 1] - offs_src_a[i];
    ii_a[i] = 1.0f / sqrtf((float)(ci < 1 ? 1 : ci));
    io_a[i] = 1.0f / sqrtf((float)(co < 1 ? 1 : co));
  }
  if (i < n_f) {
    int ci = offs_f[i + 1] - offs_f[i];
    int co = offs_src_f[i + 1] - offs_src_f[i];
    ii_f[i] = 1.0f / sqrtf((float)(ci < 1 ? 1 : ci));
    io_f[i] = 1.0f / sqrtf((float)(co < 1 ? 1 : co));
  }
}

// ---------------------------------------------------------------------------
// Hybrid bf16-MFMA GEMM: C[M,N] = epi( (A[M,K](+s*add_vec[K])) @ B[K,N] )
// Bt = pre-transposed bf16 [N][K]. Block = 4 waves x 16 rows (64 rows), each
// wave computes 16 rows x full N.
//  - A fragments: per-lane direct global loads, ALL issued at kernel top so
//    HBM latency hides under the B staging + barrier.
//  - B: cooperatively staged to LDS (row pad +8 halves -> word stride % 32
//    == 4 -> conflict-free ds_read_b128). K staged in <=128-wide chunks so
//    static LDS stays <= 35KB.
//  - MFMA operands swapped: mfma(bf, af) computes the transposed tile, so a
//    lane's acc[nt][0..3] are 4 CONSECUTIVE columns of row m (m == the row
//    this lane loaded for A). Epilogue: scalar rowscale + 8B ushort4 stores.
// epi: *rowscale[M]? +bias[N]? out bf16.
// ---------------------------------------------------------------------------
template <int K, int N, int INBF16, int ADDV>
__global__ __launch_bounds__(256) void gemm_bls_kernel(
    const void* __restrict__ A, const unsigned short* __restrict__ Bt,
    unsigned short* __restrict__ C, int M,
    const float* __restrict__ add_vec, float add_scale,
    const float* __restrict__ rowscale, const float* __restrict__ bias) {
  constexpr int KS = (K < 128) ? K : 128;  // staged K width
  constexpr int KP = KS + 8;               // padded row length (halves)
  constexpr int NT = N / 16;
  constexpr int KK = K / 32;
  constexpr int KKS = KS / 32;
  constexpr int NSTAGE = K / KS;
  constexpr int CHUNKS = (N * KS / 8) / 256;  // 16B chunks per thread
  __shared__ __align__(16) unsigned short Bs[N * KP];

  const int tid = threadIdx.x;
  const int lane = tid & 63, w = tid >> 6;
  const int q = lane >> 4, l16 = lane & 15;
  const int m0 = blockIdx.x * 64;
  const int m = m0 + w * 16 + l16;
  const int mload = (m < M) ? m : (M - 1);  // clamp; stores are guarded on m

  // ---- 1) issue ALL per-lane A-fragment loads (oldest in vmcnt queue) ----
  bf16x8 af[KK];
  if constexpr (INBF16) {
    const unsigned short* Ar = (const unsigned short*)A + (size_t)mload * K + q * 8;
#pragma unroll
    for (int kk = 0; kk < KK; ++kk)
      af[kk] = *reinterpret_cast<const bf16x8*>(Ar + kk * 32);
  } else {
    const float* Ar = (const float*)A + (size_t)mload * K + q * 8;
    float4 r0[KK], r1[KK];
#pragma unroll
    for (int kk = 0; kk < KK; ++kk) {
      r0[kk] = *reinterpret_cast<const float4*>(Ar + kk * 32);
      r1[kk] = *reinterpret_cast<const float4*>(Ar + kk * 32 + 4);
    }
#pragma unroll
    for (int kk = 0; kk < KK; ++kk) {
      bf16x8 t;
      t[0] = (short)f2bf(r0[kk].x); t[1] = (short)f2bf(r0[kk].y);
      t[2] = (short)f2bf(r0[kk].z); t[3] = (short)f2bf(r0[kk].w);
      t[4] = (short)f2bf(r1[kk].x); t[5] = (short)f2bf(r1[kk].y);
      t[6] = (short)f2bf(r1[kk].z); t[7] = (short)f2bf(r1[kk].w);
      af[kk] = t;
    }
  }
  if constexpr (ADDV) {
#pragma unroll
    for (int kk = 0; kk < KK; ++kk) {
      float4 av0 = *reinterpret_cast<const float4*>(add_vec + kk * 32 + q * 8);
      float4 av1 = *reinterpret_cast<const float4*>(add_vec + kk * 32 + q * 8 + 4);
      u16x8 u = (u16x8)af[kk];
      bf16x8 t;
      t[0] = (short)f2bf(bf2f(u[0]) + add_scale * av0.x);
      t[1] = (short)f2bf(bf2f(u[1]) + add_scale * av0.y);
      t[2] = (short)f2bf(bf2f(u[2]) + add_scale * av0.z);
      t[3] = (short)f2bf(bf2f(u[3]) + add_scale * av0.w);
      t[4] = (short)f2bf(bf2f(u[4]) + add_scale * av1.x);
      t[5] = (short)f2bf(bf2f(u[5]) + add_scale * av1.y);
      t[6] = (short)f2bf(bf2f(u[6]) + add_scale * av1.z);
      t[7] = (short)f2bf(bf2f(u[7]) + add_scale * av1.w);
      af[kk] = t;
    }
  }

  f32x4 acc[NT] = {};
#pragma unroll
  for (int st = 0; st < NSTAGE; ++st) {
    // ---- 2) cooperative B stage: Bt[:, st*KS .. st*KS+KS) -> Bs ----
    u16x8 breg[CHUNKS];
#pragma unroll
    for (int c = 0; c < CHUNKS; ++c) {
      int idx = c * 256 + tid;
      int n = idx / (KS / 8), kp = (idx % (KS / 8)) * 8;
      breg[c] = *reinterpret_cast<const u16x8*>(Bt + (size_t)n * K + st * KS + kp);
    }
    if (st) __syncthreads();  // all waves done reading previous stage
#pragma unroll
    for (int c = 0; c < CHUNKS; ++c) {
      int idx = c * 256 + tid;
      int n = idx / (KS / 8), kp = (idx % (KS / 8)) * 8;
      *reinterpret_cast<u16x8*>(&Bs[n * KP + kp]) = breg[c];
    }
    __syncthreads();
    // ---- 3) MFMA: chain waits only on LDS (and the pre-issued A regs) ----
#pragma unroll
    for (int kk = 0; kk < KKS; ++kk) {
#pragma unroll
      for (int nt = 0; nt < NT; ++nt) {
        bf16x8 bf =
            *reinterpret_cast<const bf16x8*>(&Bs[(nt * 16 + l16) * KP + kk * 32 + q * 8]);
        acc[nt] =
            __builtin_amdgcn_mfma_f32_16x16x32_bf16(bf, af[st * KKS + kk], acc[nt], 0, 0, 0);
      }
    }
  }

  // ---- 4) epilogue: row m, cols nt*16 + q*4 + {0..3} ----
  if (m < M) {
    float rs = rowscale ? rowscale[m] : 1.0f;
#pragma unroll
    for (int nt = 0; nt < NT; ++nt) {
      float4 bv;
      if (bias)
        bv = *reinterpret_cast<const float4*>(bias + nt * 16 + q * 4);
      else
        bv = make_float4(0.f, 0.f, 0.f, 0.f);
      ushort4 st4;
      st4.x = f2bf(fmaf(acc[nt][0], rs, bv.x));
      st4.y = f2bf(fmaf(acc[nt][1], rs, bv.y));
      st4.z = f2bf(fmaf(acc[nt][2], rs, bv.z));
      st4.w = f2bf(fmaf(acc[nt][3], rs, bv.w));
      *reinterpret_cast<ushort4*>(C + (size_t)m * N + nt * 16 + q * 4) = st4;
    }
  }
}

// h[node] = relu( (sum_{e in CSR[node]} XW_bf16[src(e)]) * isr_in[node] + b )
// 32 threads per node, 8 nodes/block, 4-wide unroll (4 row loads in flight).
// mode 0: write h rows bf16 to out[node*128..].
// mode 1: per-block channel SUMS  -> out[blockIdx*128..] (fp32 partials).
// mode 2: per-block channel MAXES -> out[blockIdx*128..] (fp32, h>=0).
__global__ __launch_bounds__(256) void agg_kernel(
    const unsigned short* __restrict__ XW, const int* __restrict__ offs,
    const int* __restrict__ csr, const float* __restrict__ isr_in,
    const float* __restrict__ bias, void* __restrict__ out, int n, int mode) {
  __shared__ float red[8][128];
  int lane = threadIdx.x & 31;
  int g = threadIdx.x >> 5;
  int node = blockIdx.x * 8 + g;
  float4 o = make_float4(0.f, 0.f, 0.f, 0.f);
  if (node < n) {
    int e0 = offs[node], e1 = offs[node + 1];
    float4 a0 = make_float4(0.f, 0.f, 0.f, 0.f);
    float4 a1 = a0, a2 = a0, a3 = a0;
    int e = e0;
    for (; e + 4 <= e1; e += 4) {
      int s0 = csr[e], s1 = csr[e + 1], s2 = csr[e + 2], s3 = csr[e + 3];
      ushort4 v0 = *reinterpret_cast<const ushort4*>(&XW[(size_t)s0 * 128 + lane * 4]);
      ushort4 v1 = *reinterpret_cast<const ushort4*>(&XW[(size_t)s1 * 128 + lane * 4]);
      ushort4 v2 = *reinterpret_cast<const ushort4*>(&XW[(size_t)s2 * 128 + lane * 4]);
      ushort4 v3 = *reinterpret_cast<const ushort4*>(&XW[(size_t)s3 * 128 + lane * 4]);
      a0.x += bf2f(v0.x); a0.y += bf2f(v0.y); a0.z += bf2f(v0.z); a0.w += bf2f(v0.w);
      a1.x += bf2f(v1.x); a1.y += bf2f(v1.y); a1.z += bf2f(v1.z); a1.w += bf2f(v1.w);
      a2.x += bf2f(v2.x); a2.y += bf2f(v2.y); a2.z += bf2f(v2.z); a2.w += bf2f(v2.w);
      a3.x += bf2f(v3.x); a3.y += bf2f(v3.y); a3.z += bf2f(v3.z); a3.w += bf2f(v3.w);
    }
    for (; e < e1; ++e) {
      int s = csr[e];
      ushort4 v = *reinterpret_cast<const ushort4*>(&XW[(size_t)s * 128 + lane * 4]);
      a0.x += bf2f(v.x); a0.y += bf2f(v.y); a0.z += bf2f(v.z); a0.w += bf2f(v.w);
    }
    float4 acc;
    acc.x = (a0.x + a1.x) + (a2.x + a3.x);
    acc.y = (a0.y + a1.y) + (a2.y + a3.y);
    acc.z = (a0.z + a1.z) + (a2.z + a3.z);
    acc.w = (a0.w + a1.w) + (a2.w + a3.w);
    float sc = isr_in[node];
    float4 b = *reinterpret_cast<const float4*>(&bias[lane * 4]);
    o.x = fmaxf(fmaf(acc.x, sc, b.x), 0.f);
    o.y = fmaxf(fmaf(acc.y, sc, b.y), 0.f);
    o.z = fmaxf(fmaf(acc.z, sc, b.z), 0.f);
    o.w = fmaxf(fmaf(acc.w, sc, b.w), 0.f);
  }
  if (mode == 0) {
    if (node < n) {
      ushort4 st;
      st.x = f2bf(o.x); st.y = f2bf(o.y); st.z = f2bf(o.z); st.w = f2bf(o.w);
      *reinterpret_cast<ushort4*>(&((unsigned short*)out)[(size_t)node * 128 + lane * 4]) = st;
    }
    return;
  }
  // Reduce modes: zeros from padded nodes are identity for sum and for max
  // (h >= 0 after relu).
  red[g][lane * 4 + 0] = o.x;
  red[g][lane * 4 + 1] = o.y;
  red[g][lane * 4 + 2] = o.z;
  red[g][lane * 4 + 3] = o.w;
  __syncthreads();
  if (threadIdx.x < 128) {
    float v = red[0][threadIdx.x];
    if (mode == 1) {
#pragma unroll
      for (int j = 1; j < 8; ++j) v += red[j][threadIdx.x];
    } else {
#pragma unroll
      for (int j = 1; j < 8; ++j) v = fmaxf(v, red[j][threadIdx.x]);
    }
    ((float*)out)[(size_t)blockIdx.x * 128 + threadIdx.x] = v;
  }
}

// out[col] += column sums of X[n, ncol] (fp32 or bf16); out pre-zeroed.
__global__ __launch_bounds__(256) void colsum_kernel(const void* __restrict__ X,
                                                     float* __restrict__ out, int n, int ncol,
                                                     int xbf16) {
  __shared__ float s[256];
  int col = threadIdx.x % ncol;
  int rpb = 256 / ncol;
  int rb = threadIdx.x / ncol;
  float acc = 0.f;
  for (int r = blockIdx.x * rpb + rb; r < n; r += gridDim.x * rpb) {
    size_t idx = (size_t)r * ncol + col;
    acc += xbf16 ? bf2f(((const unsigned short*)X)[idx]) : ((const float*)X)[idx];
  }
  s[threadIdx.x] = acc;
  __syncthreads();
  if (threadIdx.x < ncol) {
    float v = 0.f;
    for (int i = 0; i < rpb; ++i) v += s[threadIdx.x + i * ncol];
    atomicAdd(&out[col], v);
  }
}

// out[col] = max over rows (X >= 0; out pre-zeroed). Bit-compare trick.
__global__ __launch_bounds__(256) void colmax_kernel(const float* __restrict__ X,
                                                     unsigned* __restrict__ out, int n, int ncol) {
  __shared__ float s[256];
  int col = threadIdx.x % ncol;
  int rpb = 256 / ncol;
  int rb = threadIdx.x / ncol;
  float acc = 0.f;
  for (int r = blockIdx.x * rpb + rb; r < n; r += gridDim.x * rpb)
    acc = fmaxf(acc, X[(size_t)r * ncol + col]);
  s[threadIdx.x] = acc;
  __syncthreads();
  if (threadIdx.x < ncol) {
    float v = s[threadIdx.x];
    for (int i = 1; i < rpb; ++i) v = fmaxf(v, s[threadIdx.x + i * ncol]);
    atomicMax(&out[col], __float_as_uint(v));
  }
}

// norm_embed(a) + norm_embed(f) then @ W_cls + b_cls. Single block of 128.
__global__ __launch_bounds__(128) void final_kernel(
    const float* __restrict__ emb_a_sum, const unsigned* __restrict__ emb_f_bits,
    const float* __restrict__ W_cls, const float* __restrict__ b_cls,
    float* __restrict__ out, float inv_n_apig, int ncls) {
  __shared__ float red[128];
  __shared__ float emb[128];
  int t = threadIdx.x;
  float a = emb_a_sum[t] * inv_n_apig;
  float f = __uint_as_float(emb_f_bits[t]);

  float vals[2] = {a, f};
  float norms[2];
#pragma unroll
  for (int which = 0; which < 2; ++which) {
    float x = vals[which];
    red[t] = x;
    __syncthreads();
    for (int o = 64; o > 0; o >>= 1) {
      if (t < o) red[t] += red[t + o];
      __syncthreads();
    }
    float mean = red[0] / 128.f;
    __syncthreads();
    float d = x - mean;
    red[t] = d * d;
    __syncthreads();
    for (int o = 64; o > 0; o >>= 1) {
      if (t < o) red[t] += red[t + o];
      __syncthreads();
    }
    float stdv = sqrtf(red[0] / 127.f);  // ddof=1
    __syncthreads();
    float z = d / stdv;
    red[t] = z;
    __syncthreads();
    for (int o = 64; o > 0; o >>= 1) {
      if (t < o) red[t] = fminf(red[t], red[t + o]);
      __syncthreads();
    }
    float zmin = red[0];
    __syncthreads();
    red[t] = z;
    __syncthreads();
    for (int o = 64; o > 0; o >>= 1) {
      if (t < o) red[t] = fmaxf(red[t], red[t + o]);
      __syncthreads();
    }
    float zmax = red[0];
    __syncthreads();
    norms[which] = (z - zmin) / (zmax - zmin);
  }

  emb[t] = norms[0] + norms[1];
  __syncthreads();
  if (t < ncls) {
    float acc = b_cls[t];
    for (int k = 0; k < 128; ++k) acc = fmaf(emb[k], W_cls[k * ncls + t], acc);
    out[t] = acc;
  }
}

extern "C" void kernel_launch(void* const* d_in, const int* in_sizes, int n_in,
                              void* d_out, int out_size, void* d_ws, size_t ws_size,
                              hipStream_t stream) {
  const float* apig_feat = (const float*)d_in[0];
  const float* fcg_feat = (const float*)d_in[1];
  const float* W_a1 = (const float*)d_in[2];
  const float* b_a1 = (const float*)d_in[3];
  const float* W_a2 = (const float*)d_in[4];
  const float* b_a2 = (const float*)d_in[5];
  const float* W_f1 = (const float*)d_in[6];
  const float* b_f1 = (const float*)d_in[7];
  const float* W_f2 = (const float*)d_in[8];
  const float* b_f2 = (const float*)d_in[9];
  const float* W1 = (const float*)d_in[10];
  const float* b1 = (const float*)d_in[11];
  const float* W2 = (const float*)d_in[12];
  const float* b2 = (const float*)d_in[13];
  // d_in[14]/d_in[15] (W_attn, b_attn): dead — softmax over length-1 axis == 1.
  const float* W_cls = (const float*)d_in[16];
  const float* b_cls = (const float*)d_in[17];
  const int* a_src = (const int*)d_in[18];
  const int* a_dst = (const int*)d_in[19];
  const int* f_src = (const int*)d_in[20];
  const int* f_dst = (const int*)d_in[21];

  const int hidden = in_sizes[3];             // 128
  const int united = in_sizes[11];            // 64
  const int ncls = in_sizes[17];              // 10
  const int apig_dim = in_sizes[2] / hidden;  // 256
  const int fcg_dim = in_sizes[6] / hidden;   // 128
  const int n_a = in_sizes[0] / apig_dim;     // 50000
  const int n_f = in_sizes[1] / fcg_dim;      // 100000
  const int e_a = in_sizes[18];               // 800000
  const int e_f = in_sizes[20];               // 1600000

  // ---- workspace carve-up (all 256B aligned) ----
  char* w = (char*)d_ws;
  auto alloc = [&](size_t bytes) -> void* {
    void* p = (void*)w;
    w += (bytes + 255) & ~(size_t)255;
    return p;
  };
  const int E_tot = e_a + e_f;
  const int B = (E_tot + SORT_T - 1) / SORT_T;
  const int nblkA = (n_a + 7) / 8, nblkF = (n_f + 7) / 8;

  float* isr_out_a = (float*)alloc((size_t)n_a * 4);
  float* isr_in_a = (float*)alloc((size_t)n_a * 4);
  float* isr_out_f = (float*)alloc((size_t)n_f * 4);
  float* isr_in_f = (float*)alloc((size_t)n_f * 4);
  int* offs_a = (int*)alloc((size_t)(n_a + 1) * 4);
  int* offs_f = (int*)alloc((size_t)(n_f + 1) * 4);
  int* offs_src_a = (int*)alloc((size_t)(n_a + 1) * 4);
  int* offs_src_f = (int*)alloc((size_t)(n_f + 1) * 4);
  int* kp = (int*)alloc((size_t)E_tot * 4);   // packed dst-sort output; u16 src reuses
  int* csr = (int*)alloc((size_t)E_tot * 4);  // final CSR (apig [0,e_a), fcg [e_a,..))
  int* blkhist = (int*)alloc((size_t)512 * B * 4);
  int* bintotal = (int*)alloc((size_t)512 * 4);
  int* binstart = (int*)alloc((size_t)512 * 4);
  unsigned short* G_a = (unsigned short*)alloc((size_t)n_a * hidden * 2);  // bf16 table
  unsigned short* H_a = (unsigned short*)alloc((size_t)n_a * hidden * 2);  // h1 / a_dec (bf16)
  unsigned short* G_f = (unsigned short*)alloc((size_t)n_f * hidden * 2);
  unsigned short* H_f = (unsigned short*)alloc((size_t)n_f * hidden * 2);
  float* P = (float*)alloc((size_t)nblkF * hidden * 4);  // conv2 block partials
  unsigned short* E_a = G_a;  // enc raw (bf16, n x 64) aliases G_a (disjoint lifetimes)
  unsigned short* E_f = G_f;
  float* a_sum = (float*)alloc((size_t)united * 4);
  float* f_sum = (float*)alloc((size_t)united * 4);
  float* emb_a = (float*)alloc((size_t)hidden * 4);
  unsigned* emb_f = (unsigned*)alloc((size_t)hidden * 4);
  // bf16 [N][K] pre-transposed weights
  unsigned short* T_a1 = (unsigned short*)alloc((size_t)apig_dim * hidden * 2);
  unsigned short* T_f1 = (unsigned short*)alloc((size_t)fcg_dim * hidden * 2);
  unsigned short* T_a2 = (unsigned short*)alloc((size_t)hidden * hidden * 2);
  unsigned short* T_f2 = (unsigned short*)alloc((size_t)hidden * hidden * 2);
  unsigned short* T1 = (unsigned short*)alloc((size_t)hidden * united * 2);
  unsigned short* T2 = (unsigned short*)alloc((size_t)united * hidden * 2);
  int* csr_a = csr;
  int* csr_f = csr + e_a;
  unsigned short* ks = (unsigned short*)kp;  // src-sort u16 keys (after dst sort done)
  (void)ws_size;
  (void)n_in;
  (void)out_size;

  dim3 blk(256);

  // ---- init tiny accumulators + offs sentinels; weight transpose prep ----
  zero_small_kernel<<<1, 128, 0, stream>>>(a_sum, f_sum, united, emb_a, emb_f, hidden,
                                           offs_a, offs_src_a, n_a, e_a,
                                           offs_f, offs_src_f, n_f, e_f);
  prep_bt_kernel<<<dim3(32, 6), blk, 0, stream>>>(W_a1, W_f1, W_a2, W_f2, W1, W2,
                                                  T_a1, T_f1, T_a2, T_f2, T1, T2);

  // ---- CSR build: dst sort (hist -> cursor -> binscan -> scatter -> bucket) ----
  radix_hist_kernel<<<B, blk, 0, stream>>>(a_dst, f_dst, e_a, E_tot, blkhist, B);
  cursor_kernel<<<512, blk, 0, stream>>>(blkhist, B, bintotal);
  binscan_kernel<<<1, blk, 0, stream>>>(bintotal, binstart);
  scatter_dst_kernel<<<B, blk, 0, stream>>>(a_dst, f_dst, a_src, f_src, e_a, E_tot,
                                            blkhist, B, binstart, kp);
  bucket_dst_kernel<<<512, blk, 0, stream>>>(kp, binstart, E_tot, e_a,
                                             csr, offs_a, n_a, offs_f, n_f);
  // ---- src sort (keys only) -> offs_src (out-degrees) ----
  radix_hist_kernel<<<B, blk, 0, stream>>>(a_src, f_src, e_a, E_tot, blkhist, B);
  cursor_kernel<<<512, blk, 0, stream>>>(blkhist, B, bintotal);
  binscan_kernel<<<1, blk, 0, stream>>>(bintotal, binstart);
  scatter_src_kernel<<<B, blk, 0, stream>>>(a_src, f_src, e_a, E_tot, blkhist, B,
                                            binstart, ks);
  bucket_src_kernel<<<512, blk, 0, stream>>>(ks, binstart, E_tot, e_a,
                                             offs_src_a, n_a, offs_src_f, n_f);
  isr_kernel<<<(n_f + 255) / 256, blk, 0, stream>>>(offs_a, offs_src_a, isr_out_a, isr_in_a,
                                                    n_a, offs_f, offs_src_f, isr_out_f,
                                                    isr_in_f, n_f);

  const int ga = (n_a + 63) / 64, gf = (n_f + 63) / 64;

  // ---- apig conv1 + enc ----
  gemm_bls_kernel<256, 128, 0, 0><<<ga, blk, 0, stream>>>(
      apig_feat, T_a1, G_a, n_a, nullptr, 0.f, isr_out_a, nullptr);
  agg_kernel<<<nblkA, blk, 0, stream>>>(G_a, offs_a, csr_a, isr_in_a, b_a1, H_a, n_a, 0);
  gemm_bls_kernel<128, 64, 1, 0><<<ga, blk, 0, stream>>>(
      H_a, T1, E_a, n_a, nullptr, 0.f, nullptr, b1);  // E_a=G_a (dead)
  colsum_kernel<<<256, blk, 0, stream>>>(E_a, a_sum, n_a, united, 1);

  // ---- fcg conv1 + enc ----
  gemm_bls_kernel<128, 128, 0, 0><<<gf, blk, 0, stream>>>(
      fcg_feat, T_f1, G_f, n_f, nullptr, 0.f, isr_out_f, nullptr);
  agg_kernel<<<nblkF, blk, 0, stream>>>(G_f, offs_f, csr_f, isr_in_f, b_f1, H_f, n_f, 0);
  gemm_bls_kernel<128, 64, 1, 0><<<gf, blk, 0, stream>>>(
      H_f, T1, E_f, n_f, nullptr, 0.f, nullptr, b1);
  colsum_kernel<<<256, blk, 0, stream>>>(E_f, f_sum, n_f, united, 1);

  // ---- apig dec + conv2 + mean (H2 never materialized) ----
  gemm_bls_kernel<64, 128, 1, 1><<<ga, blk, 0, stream>>>(
      E_a, T2, H_a, n_a, f_sum, 0.1f, nullptr, b2);  // a_dec -> H_a
  gemm_bls_kernel<128, 128, 1, 0><<<ga, blk, 0, stream>>>(
      H_a, T_a2, G_a, n_a, nullptr, 0.f, isr_out_a, nullptr);
  agg_kernel<<<nblkA, blk, 0, stream>>>(G_a, offs_a, csr_a, isr_in_a, b_a2, P, n_a, 1);
  colsum_kernel<<<256, blk, 0, stream>>>(P, emb_a, nblkA, hidden, 0);

  // ---- fcg dec + conv2 + max ----
  gemm_bls_kernel<64, 128, 1, 1><<<gf, blk, 0, stream>>>(
      E_f, T2, H_f, n_f, a_sum, 0.1f, nullptr, b2);  // f_dec -> H_f
  gemm_bls_kernel<128, 128, 1, 0><<<gf, blk, 0, stream>>>(
      H_f, T_f2, G_f, n_f, nullptr, 0.f, isr_out_f, nullptr);
  agg_kernel<<<nblkF, blk, 0, stream>>>(G_f, offs_f, csr_f, isr_in_f, b_f2, P, n_f, 2);
  colmax_kernel<<<256, blk, 0, stream>>>(P, emb_f, nblkF, hidden);

  // ---- head ----
  final_kernel<<<1, 128, 0, stream>>>(emb_a, emb_f, W_cls, b_cls, (float*)d_out,
                                      1.0f / (float)n_a, ncls);
}

// Round 3
// 570.738 us; speedup vs baseline: 1.4124x; 1.1621x over previous
//
#include <hip/hip_runtime.h>
#include <math.h>

// ---------------------------------------------------------------------------
// MultiGraphClassifier on MI355X.
// Pipeline: 2x GraphConv per graph + cross-graph fusion + tiny head.
// Strategy: ATOMIC-FREE CSR build via MSD radix bucketing + per-bucket LDS
// counting sort; gather-side aggregation over bf16 tables; bf16-MFMA GEMMs
// with fp32 accumulate and fused epilogues. All node intermediates bf16.
// conv2's H never materialized: agg reduces per-block channel partials.
// Note: softmax over a length-1 axis == 1.0, so emb = norm(a) + norm(f).
// R1-R10: see history. R8/R9: radix sort, decoupled scan. R10: bf16 tables.
// R11 FALSIFIED: LDS-free GEMM is latency-bound (MfmaUtil 1.7%).
// R12: hybrid GEMM (B in LDS staged once, A direct-to-reg issued first,
//   swapped MFMA operands -> row-major epilogue). 806 -> 663us.
// R13: FUSION. ~30 serialized dispatches/iter exceeded modeled kernel time
//   by ~300us -> attack launch/serialization overhead:
//   - dst+src sorts fused: hist2 (one edge pass, 2 LDS histograms),
//     cursor2 (1024 blks), scatter2 (one edge pass, 8B/edge, scatters both),
//     bucket2 (1024 blks). binscan ELIMINATED (consumers re-derive binstart
//     via in-block 512-scan of bintotal).
//   - apig+fcg merged dispatches: agg (block-range select), W1/dec/conv2
//     GEMMs, colsums, zero+prep. Launches/iter: ~30 -> 16.
// ---------------------------------------------------------------------------

typedef __attribute__((ext_vector_type(8))) short bf16x8;
typedef __attribute__((ext_vector_type(8))) unsigned short u16x8;
typedef __attribute__((ext_vector_type(4))) float f32x4;

#define SORT_T 4096  // edges per phase-1 block

static __device__ inline unsigned short f2bf(float f) {
  unsigned u = __float_as_uint(f);
  unsigned r = (u + 0x7fff + ((u >> 16) & 1)) >> 16;  // RNE
  return (unsigned short)r;
}
static __device__ inline float bf2f(unsigned short h) {
  return __uint_as_float(((unsigned)h) << 16);
}

// Inclusive Hillis-Steele scan over 512 LDS ints, 256 threads.
// Caller must __syncthreads() after loading x and before calling.
static __device__ inline void scan512(int* x) {
  for (int o = 1; o < 512; o <<= 1) {
    int i0 = threadIdx.x, i1 = threadIdx.x + 256;
    int v0 = (i0 >= o) ? x[i0 - o] : 0;
    int v1 = (i1 >= o) ? x[i1 - o] : 0;
    __syncthreads();
    x[i0] += v0;
    x[i1] += v1;
    __syncthreads();
  }
}

// One-time: zero tiny accumulators + offs sentinels (block (0,0)) and
// Bt[n*K + k] = bf16(W[k*N + n]) for the 6 GEMM weights.
__global__ __launch_bounds__(256) void prep_init_kernel(
    const float* __restrict__ W_a1, const float* __restrict__ W_f1,
    const float* __restrict__ W_a2, const float* __restrict__ W_f2,
    const float* __restrict__ W1, const float* __restrict__ W2,
    unsigned short* __restrict__ T_a1, unsigned short* __restrict__ T_f1,
    unsigned short* __restrict__ T_a2, unsigned short* __restrict__ T_f2,
    unsigned short* __restrict__ T1, unsigned short* __restrict__ T2,
    float* __restrict__ s0, float* __restrict__ s1, int ns,
    float* __restrict__ ea, unsigned* __restrict__ ef, int ne,
    int* __restrict__ offs_a, int* __restrict__ offs_src_a, int n_a, int e_a,
    int* __restrict__ offs_f, int* __restrict__ offs_src_f, int n_f, int e_f) {
  if (blockIdx.x == 0 && blockIdx.y == 0) {
    int i = threadIdx.x;
    if (i < ns) { s0[i] = 0.f; s1[i] = 0.f; }
    if (i < ne) { ea[i] = 0.f; ef[i] = 0u; }
    if (i == 0) {
      offs_a[n_a] = e_a;
      offs_src_a[n_a] = e_a;
      offs_f[n_f] = e_f;
      offs_src_f[n_f] = e_f;
    }
  }
  const float* src;
  unsigned short* dst;
  int K, N;
  switch (blockIdx.y) {
    case 0: src = W_a1; dst = T_a1; K = 256; N = 128; break;
    case 1: src = W_f1; dst = T_f1; K = 128; N = 128; break;
    case 2: src = W_a2; dst = T_a2; K = 128; N = 128; break;
    case 3: src = W_f2; dst = T_f2; K = 128; N = 128; break;
    case 4: src = W1;   dst = T1;   K = 128; N = 64;  break;
    default: src = W2;  dst = T2;   K = 64;  N = 128; break;
  }
  int total = K * N;
  for (int idx = blockIdx.x * 256 + threadIdx.x; idx < total; idx += gridDim.x * 256) {
    int n = idx / K, k = idx - n * K;
    dst[idx] = f2bf(src[(size_t)k * N + n]);
  }
}

// Fused phase-1 histogram over high 9 bits for BOTH dst and src keys.
// One pass over the edge arrays; LDS atomics only.
__global__ __launch_bounds__(256) void hist2_kernel(
    const int* __restrict__ a_dst, const int* __restrict__ f_dst,
    const int* __restrict__ a_src, const int* __restrict__ f_src,
    int e_a, int E, int* __restrict__ blkhistD, int* __restrict__ blkhistS, int B) {
  __shared__ int hD[512], hS[512];
  for (int i = threadIdx.x; i < 512; i += 256) { hD[i] = 0; hS[i] = 0; }
  __syncthreads();
  int base = blockIdx.x * SORT_T;
  int end = base + SORT_T;
  if (end > E) end = E;
  for (int i = base + threadIdx.x; i < end; i += 256) {
    int kD = (i < e_a) ? a_dst[i] : (f_dst[i - e_a] + 65536);
    int kS = (i < e_a) ? a_src[i] : (f_src[i - e_a] + 65536);
    atomicAdd(&hD[kD >> 9], 1);
    atomicAdd(&hS[kS >> 9], 1);
  }
  __syncthreads();
  for (int i = threadIdx.x; i < 512; i += 256) {
    blkhistD[i * B + blockIdx.x] = hD[i];
    blkhistS[i * B + blockIdx.x] = hS[i];
  }
}

// One block per (bin, D|S): exclusive prefix over the bin's B block-counts
// (in place) + bin total. Grid = 1024.
__global__ __launch_bounds__(256) void cursor2_kernel(
    int* __restrict__ blkhistD, int* __restrict__ blkhistS, int B,
    int* __restrict__ bintotalD, int* __restrict__ bintotalS) {
  __shared__ int part[256];
  int isD = blockIdx.x < 512;
  int bin = isD ? blockIdx.x : blockIdx.x - 512;
  int* row = (isD ? blkhistD : blkhistS) + (size_t)bin * B;
  int C = (B + 255) / 256;
  int start = threadIdx.x * C;
  int end = start + C;
  if (end > B) end = B;
  int v[8];  // C <= 8 for B <= 2048
  int s = 0;
  for (int j = start; j < end; ++j) {
    v[j - start] = row[j];
    s += v[j - start];
  }
  part[threadIdx.x] = s;
  __syncthreads();
  for (int o = 1; o < 256; o <<= 1) {
    int u = (threadIdx.x >= o) ? part[threadIdx.x - o] : 0;
    __syncthreads();
    part[threadIdx.x] += u;
    __syncthreads();
  }
  int run = part[threadIdx.x] - s;  // exclusive
  for (int j = start; j < end; ++j) {
    row[j] = run;
    run += v[j - start];
  }
  if (threadIdx.x == 255) (isD ? bintotalD : bintotalS)[bin] = part[255];
}

// Fused phase-1 scatter: one pass over edges, scatters BOTH the dst-sort
// packed records and the src-sort u16 keys. binstart derived in-block by
// scanning bintotal (kills the binscan kernel).
__global__ __launch_bounds__(256) void scatter2_kernel(
    const int* __restrict__ a_dst, const int* __restrict__ f_dst,
    const int* __restrict__ a_src, const int* __restrict__ f_src,
    int e_a, int E, const int* __restrict__ blkhistD, const int* __restrict__ blkhistS,
    int B, const int* __restrict__ bintotalD, const int* __restrict__ bintotalS,
    int* __restrict__ opack, unsigned short* __restrict__ okey) {
  __shared__ int curD[512], curS[512], tmp[512];
  int b = blockIdx.x, tid = threadIdx.x;
  tmp[tid] = bintotalD[tid];
  tmp[tid + 256] = bintotalD[tid + 256];
  __syncthreads();
  scan512(tmp);
  curD[tid] = tmp[tid] - bintotalD[tid] + blkhistD[tid * B + b];
  curD[tid + 256] = tmp[tid + 256] - bintotalD[tid + 256] + blkhistD[(tid + 256) * B + b];
  __syncthreads();
  tmp[tid] = bintotalS[tid];
  tmp[tid + 256] = bintotalS[tid + 256];
  __syncthreads();
  scan512(tmp);
  curS[tid] = tmp[tid] - bintotalS[tid] + blkhistS[tid * B + b];
  curS[tid + 256] = tmp[tid + 256] - bintotalS[tid + 256] + blkhistS[(tid + 256) * B + b];
  __syncthreads();
  int base = b * SORT_T;
  int end = base + SORT_T;
  if (end > E) end = E;
  for (int i = base + tid; i < end; i += 256) {
    int sv = (i < e_a) ? a_src[i] : f_src[i - e_a];
    int kD = (i < e_a) ? a_dst[i] : (f_dst[i - e_a] + 65536);
    int kS = (i < e_a) ? sv : (sv + 65536);
    int posD = atomicAdd(&curD[kD >> 9], 1);
    opack[posD] = ((kD & 511) << 17) | sv;
    int posS = atomicAdd(&curS[kS >> 9], 1);
    okey[posS] = (unsigned short)(kS & 511);
  }
}

// Fused phase-2: blocks [0,512) = dst buckets (LDS counting sort -> csr +
// offs), blocks [512,1024) = src buckets (hist+scan -> offs_src only).
// binstart re-derived in-block from bintotal.
__global__ __launch_bounds__(256) void bucket2_kernel(
    const int* __restrict__ kp, const unsigned short* __restrict__ ks,
    const int* __restrict__ bintotalD, const int* __restrict__ bintotalS,
    int E, int e_a,
    int* __restrict__ csr, int* __restrict__ offs_a, int n_a,
    int* __restrict__ offs_f, int n_f,
    int* __restrict__ offs_src_a, int* __restrict__ offs_src_f) {
  __shared__ int sh0[512], sh1[512], sh2[512];
  int tid = threadIdx.x;
  int isD = blockIdx.x < 512;
  int b = isD ? blockIdx.x : blockIdx.x - 512;
  const int* bt = isD ? bintotalD : bintotalS;
  sh0[tid] = bt[tid];
  sh0[tid + 256] = bt[tid + 256];
  __syncthreads();
  scan512(sh0);
  int e = sh0[b];
  int s = e - bt[b];
  // hist over this bucket's low-9 keys
  sh1[tid] = 0;
  sh1[tid + 256] = 0;
  __syncthreads();
  if (isD) {
    for (int i = s + tid; i < e; i += 256) atomicAdd(&sh1[kp[i] >> 17], 1);
  } else {
    for (int i = s + tid; i < e; i += 256) atomicAdd(&sh1[ks[i]], 1);
  }
  __syncthreads();
  sh2[tid] = sh1[tid];
  sh2[tid + 256] = sh1[tid + 256];
  __syncthreads();
  scan512(sh2);
  for (int low = tid; low < 512; low += 256) {
    int gpos = s + sh2[low] - sh1[low];  // exclusive start of this key's run
    int key = (b << 9) | low;
    if (isD) {
      sh0[low] = gpos;  // cursor for the final scatter
      if (key < 65536) {
        if (key < n_a) offs_a[key] = gpos;
      } else {
        int v = key - 65536;
        if (v < n_f) offs_f[v] = gpos - e_a;
      }
    } else {
      if (key < 65536) {
        if (key < n_a) offs_src_a[key] = gpos;
      } else {
        int v = key - 65536;
        if (v < n_f) offs_src_f[v] = gpos - e_a;
      }
    }
  }
  if (isD) {
    __syncthreads();
    for (int i = s + tid; i < e; i += 256) {
      int pv = kp[i];
      int pos = atomicAdd(&sh0[pv >> 17], 1);
      csr[pos] = pv & 0x1FFFF;
    }
  }
}

// isr from offs diffs (needs sentinels).
__global__ void isr_kernel(const int* __restrict__ offs_a, const int* __restrict__ offs_src_a,
                           float* __restrict__ io_a, float* __restrict__ ii_a, int n_a,
                           const int* __restrict__ offs_f, const int* __restrict__ offs_src_f,
                           float* __restrict__ io_f, float* __restrict__ ii_f, int n_f) {
  int i = blockIdx.x * blockDim.x + threadIdx.x;
  if (i < n_a) {
    int ci = offs_a[i + 1] - offs_a[i];
    int co = offs_src_a[i + 1] - offs_src_a[i];
    ii_a[i] = 1.0f / sqrtf((float)(ci < 1 ? 1 : ci));
    io_a[i] = 1.0f / sqrtf((float)(co < 1 ? 1 : co));
  }
  if (i < n_f) {
    int ci = offs_f[i + 1] - offs_f[i];
    int co = offs_src_f[i + 1] - offs_src_f[i];
    ii_f[i] = 1.0f / sqrtf((float)(ci < 1 ? 1 : ci));
    io_f[i] = 1.0f / sqrtf((float)(co < 1 ? 1 : co));
  }
}

// ---------------------------------------------------------------------------
// Hybrid bf16-MFMA GEMM core (R12): B staged to LDS (+8 half pad), A direct
// per-lane loads issued first, swapped MFMA operands -> row-major epilogue.
// ---------------------------------------------------------------------------
template <int K, int N, int INBF16, int ADDV>
static __device__ inline void gemm_body(
    const void* __restrict__ A, const unsigned short* __restrict__ Bt,
    unsigned short* __restrict__ C, int M, int bid,
    const float* __restrict__ add_vec, float add_scale,
    const float* __restrict__ rowscale, const float* __restrict__ bias,
    unsigned short* Bs) {
  constexpr int KS = (K < 128) ? K : 128;  // staged K width
  constexpr int KP = KS + 8;               // padded row length (halves)
  constexpr int NT = N / 16;
  constexpr int KK = K / 32;
  constexpr int KKS = KS / 32;
  constexpr int NSTAGE = K / KS;
  constexpr int CHUNKS = (N * KS / 8) / 256;  // 16B chunks per thread

  const int tid = threadIdx.x;
  const int lane = tid & 63, w = tid >> 6;
  const int q = lane >> 4, l16 = lane & 15;
  const int m0 = bid * 64;
  const int m = m0 + w * 16 + l16;
  const int mload = (m < M) ? m : (M - 1);  // clamp; stores are guarded on m

  // ---- 1) issue ALL per-lane A-fragment loads (oldest in vmcnt queue) ----
  bf16x8 af[KK];
  if constexpr (INBF16) {
    const unsigned short* Ar = (const unsigned short*)A + (size_t)mload * K + q * 8;
#pragma unroll
    for (int kk = 0; kk < KK; ++kk)
      af[kk] = *reinterpret_cast<const bf16x8*>(Ar + kk * 32);
  } else {
    const float* Ar = (const float*)A + (size_t)mload * K + q * 8;
    float4 r0[KK], r1[KK];
#pragma unroll
    for (int kk = 0; kk < KK; ++kk) {
      r0[kk] = *reinterpret_cast<const float4*>(Ar + kk * 32);
      r1[kk] = *reinterpret_cast<const float4*>(Ar + kk * 32 + 4);
    }
#pragma unroll
    for (int kk = 0; kk < KK; ++kk) {
      bf16x8 t;
      t[0] = (short)f2bf(r0[kk].x); t[1] = (short)f2bf(r0[kk].y);
      t[2] = (short)f2bf(r0[kk].z); t[3] = (short)f2bf(r0[kk].w);
      t[4] = (short)f2bf(r1[kk].x); t[5] = (short)f2bf(r1[kk].y);
      t[6] = (short)f2bf(r1[kk].z); t[7] = (short)f2bf(r1[kk].w);
      af[kk] = t;
    }
  }
  if constexpr (ADDV) {
#pragma unroll
    for (int kk = 0; kk < KK; ++kk) {
      float4 av0 = *reinterpret_cast<const float4*>(add_vec + kk * 32 + q * 8);
      float4 av1 = *reinterpret_cast<const float4*>(add_vec + kk * 32 + q * 8 + 4);
      u16x8 u = (u16x8)af[kk];
      bf16x8 t;
      t[0] = (short)f2bf(bf2f(u[0]) + add_scale * av0.x);
      t[1] = (short)f2bf(bf2f(u[1]) + add_scale * av0.y);
      t[2] = (short)f2bf(bf2f(u[2]) + add_scale * av0.z);
      t[3] = (short)f2bf(bf2f(u[3]) + add_scale * av0.w);
      t[4] = (short)f2bf(bf2f(u[4]) + add_scale * av1.x);
      t[5] = (short)f2bf(bf2f(u[5]) + add_scale * av1.y);
      t[6] = (short)f2bf(bf2f(u[6]) + add_scale * av1.z);
      t[7] = (short)f2bf(bf2f(u[7]) + add_scale * av1.w);
      af[kk] = t;
    }
  }

  f32x4 acc[NT] = {};
#pragma unroll
  for (int st = 0; st < NSTAGE; ++st) {
    // ---- 2) cooperative B stage: Bt[:, st*KS ..) -> Bs ----
    u16x8 breg[CHUNKS];
#pragma unroll
    for (int c = 0; c < CHUNKS; ++c) {
      int idx = c * 256 + tid;
      int n = idx / (KS / 8), kpos = (idx % (KS / 8)) * 8;
      breg[c] = *reinterpret_cast<const u16x8*>(Bt + (size_t)n * K + st * KS + kpos);
    }
    if (st) __syncthreads();  // all waves done reading previous stage
#pragma unroll
    for (int c = 0; c < CHUNKS; ++c) {
      int idx = c * 256 + tid;
      int n = idx / (KS / 8), kpos = (idx % (KS / 8)) * 8;
      *reinterpret_cast<u16x8*>(&Bs[n * KP + kpos]) = breg[c];
    }
    __syncthreads();
    // ---- 3) MFMA: chain waits only on LDS (and the pre-issued A regs) ----
#pragma unroll
    for (int kk = 0; kk < KKS; ++kk) {
#pragma unroll
      for (int nt = 0; nt < NT; ++nt) {
        bf16x8 bf =
            *reinterpret_cast<const bf16x8*>(&Bs[(nt * 16 + l16) * KP + kk * 32 + q * 8]);
        acc[nt] =
            __builtin_amdgcn_mfma_f32_16x16x32_bf16(bf, af[st * KKS + kk], acc[nt], 0, 0, 0);
      }
    }
  }

  // ---- 4) epilogue: row m, cols nt*16 + q*4 + {0..3} ----
  if (m < M) {
    float rs = rowscale ? rowscale[m] : 1.0f;
#pragma unroll
    for (int nt = 0; nt < NT; ++nt) {
      float4 bv;
      if (bias)
        bv = *reinterpret_cast<const float4*>(bias + nt * 16 + q * 4);
      else
        bv = make_float4(0.f, 0.f, 0.f, 0.f);
      ushort4 st4;
      st4.x = f2bf(fmaf(acc[nt][0], rs, bv.x));
      st4.y = f2bf(fmaf(acc[nt][1], rs, bv.y));
      st4.z = f2bf(fmaf(acc[nt][2], rs, bv.z));
      st4.w = f2bf(fmaf(acc[nt][3], rs, bv.w));
      *reinterpret_cast<ushort4*>(C + (size_t)m * N + nt * 16 + q * 4) = st4;
    }
  }
}

// Single-graph GEMM (conv1: A fp32, shapes differ per graph).
template <int K, int N, int INBF16, int ADDV>
__global__ __launch_bounds__(256) void gemm_bls_kernel(
    const void* __restrict__ A, const unsigned short* __restrict__ Bt,
    unsigned short* __restrict__ C, int M,
    const float* __restrict__ add_vec, float add_scale,
    const float* __restrict__ rowscale, const float* __restrict__ bias) {
  constexpr int KS = (K < 128) ? K : 128;
  __shared__ __align__(16) unsigned short Bs[N * (KS + 8)];
  gemm_body<K, N, INBF16, ADDV>(A, Bt, C, M, blockIdx.x, add_vec, add_scale,
                                rowscale, bias, Bs);
}

// Merged two-graph GEMM: blocks [0,gblk) = graph 0, rest = graph 1.
template <int K, int N, int INBF16, int ADDV>
__global__ __launch_bounds__(256) void gemm_bls2_kernel(
    const void* __restrict__ A0, const unsigned short* __restrict__ Bt0,
    unsigned short* __restrict__ C0, int M0,
    const void* __restrict__ A1, const unsigned short* __restrict__ Bt1,
    unsigned short* __restrict__ C1, int M1,
    const float* __restrict__ av0, const float* __restrict__ av1, float add_scale,
    const float* __restrict__ rs0, const float* __restrict__ rs1,
    const float* __restrict__ bias, int gblk) {
  constexpr int KS = (K < 128) ? K : 128;
  __shared__ __align__(16) unsigned short Bs[N * (KS + 8)];
  if ((int)blockIdx.x < gblk) {
    gemm_body<K, N, INBF16, ADDV>(A0, Bt0, C0, M0, blockIdx.x, av0, add_scale,
                                  rs0, bias, Bs);
  } else {
    gemm_body<K, N, INBF16, ADDV>(A1, Bt1, C1, M1, blockIdx.x - gblk, av1, add_scale,
                                  rs1, bias, Bs);
  }
}

// h[node] = relu( (sum_{e in CSR[node]} XW_bf16[src(e)]) * isr_in[node] + b )
// 32 threads per node, 8 nodes/block, 4-wide unroll. Merged two-graph form:
// blocks [0,nblk0) = graph 0, rest = graph 1. Per-graph mode:
// mode 0: write h rows bf16; mode 1: per-block channel SUMS (fp32);
// mode 2: per-block channel MAXES (fp32, h>=0).
__global__ __launch_bounds__(256) void agg2_kernel(
    const unsigned short* __restrict__ XW0, const int* __restrict__ offs0,
    const int* __restrict__ csr0, const float* __restrict__ isr0,
    const float* __restrict__ bias0, void* __restrict__ out0, int n0, int mode0,
    const unsigned short* __restrict__ XW1, const int* __restrict__ offs1,
    const int* __restrict__ csr1, const float* __restrict__ isr1,
    const float* __restrict__ bias1, void* __restrict__ out1, int n1, int mode1,
    int nblk0) {
  __shared__ float red[8][128];
  const unsigned short* XW;
  const int *offs, *csr;
  const float *isr_in, *bias;
  void* out;
  int n, mode, bid;
  if ((int)blockIdx.x < nblk0) {
    XW = XW0; offs = offs0; csr = csr0; isr_in = isr0; bias = bias0;
    out = out0; n = n0; mode = mode0; bid = blockIdx.x;
  } else {
    XW = XW1; offs = offs1; csr = csr1; isr_in = isr1; bias = bias1;
    out = out1; n = n1; mode = mode1; bid = blockIdx.x - nblk0;
  }
  int lane = threadIdx.x & 31;
  int g = threadIdx.x >> 5;
  int node = bid * 8 + g;
  float4 o = make_float4(0.f, 0.f, 0.f, 0.f);
  if (node < n) {
    int e0 = offs[node], e1 = offs[node + 1];
    float4 a0 = make_float4(0.f, 0.f, 0.f, 0.f);
    float4 a1 = a0, a2 = a0, a3 = a0;
    int e = e0;
    for (; e + 4 <= e1; e += 4) {
      int s0 = csr[e], s1 = csr[e + 1], s2 = csr[e + 2], s3 = csr[e + 3];
      ushort4 v0 = *reinterpret_cast<const ushort4*>(&XW[(size_t)s0 * 128 + lane * 4]);
      ushort4 v1 = *reinterpret_cast<const ushort4*>(&XW[(size_t)s1 * 128 + lane * 4]);
      ushort4 v2 = *reinterpret_cast<const ushort4*>(&XW[(size_t)s2 * 128 + lane * 4]);
      ushort4 v3 = *reinterpret_cast<const ushort4*>(&XW[(size_t)s3 * 128 + lane * 4]);
      a0.x += bf2f(v0.x); a0.y += bf2f(v0.y); a0.z += bf2f(v0.z); a0.w += bf2f(v0.w);
      a1.x += bf2f(v1.x); a1.y += bf2f(v1.y); a1.z += bf2f(v1.z); a1.w += bf2f(v1.w);
      a2.x += bf2f(v2.x); a2.y += bf2f(v2.y); a2.z += bf2f(v2.z); a2.w += bf2f(v2.w);
      a3.x += bf2f(v3.x); a3.y += bf2f(v3.y); a3.z += bf2f(v3.z); a3.w += bf2f(v3.w);
    }
    for (; e < e1; ++e) {
      int s = csr[e];
      ushort4 v = *reinterpret_cast<const ushort4*>(&XW[(size_t)s * 128 + lane * 4]);
      a0.x += bf2f(v.x); a0.y += bf2f(v.y); a0.z += bf2f(v.z); a0.w += bf2f(v.w);
    }
    float4 acc;
    acc.x = (a0.x + a1.x) + (a2.x + a3.x);
    acc.y = (a0.y + a1.y) + (a2.y + a3.y);
    acc.z = (a0.z + a1.z) + (a2.z + a3.z);
    acc.w = (a0.w + a1.w) + (a2.w + a3.w);
    float sc = isr_in[node];
    float4 b = *reinterpret_cast<const float4*>(&bias[lane * 4]);
    o.x = fmaxf(fmaf(acc.x, sc, b.x), 0.f);
    o.y = fmaxf(fmaf(acc.y, sc, b.y), 0.f);
    o.z = fmaxf(fmaf(acc.z, sc, b.z), 0.f);
    o.w = fmaxf(fmaf(acc.w, sc, b.w), 0.f);
  }
  if (mode == 0) {
    if (node < n) {
      ushort4 st;
      st.x = f2bf(o.x); st.y = f2bf(o.y); st.z = f2bf(o.z); st.w = f2bf(o.w);
      *reinterpret_cast<ushort4*>(&((unsigned short*)out)[(size_t)node * 128 + lane * 4]) = st;
    }
    return;
  }
  // Reduce modes: zeros from padded nodes are identity for sum and max (h>=0).
  red[g][lane * 4 + 0] = o.x;
  red[g][lane * 4 + 1] = o.y;
  red[g][lane * 4 + 2] = o.z;
  red[g][lane * 4 + 3] = o.w;
  __syncthreads();
  if (threadIdx.x < 128) {
    float v = red[0][threadIdx.x];
    if (mode == 1) {
#pragma unroll
      for (int j = 1; j < 8; ++j) v += red[j][threadIdx.x];
    } else {
#pragma unroll
      for (int j = 1; j < 8; ++j) v = fmaxf(v, red[j][threadIdx.x]);
    }
    ((float*)out)[(size_t)bid * 128 + threadIdx.x] = v;
  }
}

// Merged column sums of E_a (-> a_sum) and E_f (-> f_sum), bf16 in, 256
// blocks per graph; out pre-zeroed.
__global__ __launch_bounds__(256) void colsum2_kernel(
    const unsigned short* __restrict__ X0, float* __restrict__ out0, int n0,
    const unsigned short* __restrict__ X1, float* __restrict__ out1, int n1,
    int ncol) {
  __shared__ float s[256];
  const unsigned short* X;
  float* out;
  int n, bid;
  if ((int)blockIdx.x < 256) { X = X0; out = out0; n = n0; bid = blockIdx.x; }
  else { X = X1; out = out1; n = n1; bid = blockIdx.x - 256; }
  int col = threadIdx.x % ncol;
  int rpb = 256 / ncol;
  int rb = threadIdx.x / ncol;
  float acc = 0.f;
  for (int r = bid * rpb + rb; r < n; r += 256 * rpb)
    acc += bf2f(X[(size_t)r * ncol + col]);
  s[threadIdx.x] = acc;
  __syncthreads();
  if (threadIdx.x < ncol) {
    float v = 0.f;
    for (int i = 0; i < rpb; ++i) v += s[threadIdx.x + i * ncol];
    atomicAdd(&out[col], v);
  }
}

// Merged P reductions: blocks [0,256) colsum P_a -> emb_a (fp32 add),
// blocks [256,512) colmax P_f -> emb_f (bit-max; X >= 0). out pre-zeroed.
__global__ __launch_bounds__(256) void colfin_kernel(
    const float* __restrict__ Pa, float* __restrict__ emb_a, int na,
    const float* __restrict__ Pf, unsigned* __restrict__ emb_f, int nf, int ncol) {
  __shared__ float s[256];
  int isSum = blockIdx.x < 256;
  const float* X = isSum ? Pa : Pf;
  int n = isSum ? na : nf;
  int bid = isSum ? blockIdx.x : blockIdx.x - 256;
  int col = threadIdx.x % ncol;
  int rpb = 256 / ncol;
  int rb = threadIdx.x / ncol;
  float acc = 0.f;
  if (isSum) {
    for (int r = bid * rpb + rb; r < n; r += 256 * rpb) acc += X[(size_t)r * ncol + col];
  } else {
    for (int r = bid * rpb + rb; r < n; r += 256 * rpb)
      acc = fmaxf(acc, X[(size_t)r * ncol + col]);
  }
  s[threadIdx.x] = acc;
  __syncthreads();
  if (threadIdx.x < ncol) {
    if (isSum) {
      float v = 0.f;
      for (int i = 0; i < rpb; ++i) v += s[threadIdx.x + i * ncol];
      atomicAdd(&emb_a[col], v);
    } else {
      float v = s[threadIdx.x];
      for (int i = 1; i < rpb; ++i) v = fmaxf(v, s[threadIdx.x + i * ncol]);
      atomicMax(&emb_f[col], __float_as_uint(v));
    }
  }
}

// norm_embed(a) + norm_embed(f) then @ W_cls + b_cls. Single block of 128.
__global__ __launch_bounds__(128) void final_kernel(
    const float* __restrict__ emb_a_sum, const unsigned* __restrict__ emb_f_bits,
    const float* __restrict__ W_cls, const float* __restrict__ b_cls,
    float* __restrict__ out, float inv_n_apig, int ncls) {
  __shared__ float red[128];
  __shared__ float emb[128];
  int t = threadIdx.x;
  float a = emb_a_sum[t] * inv_n_apig;
  float f = __uint_as_float(emb_f_bits[t]);

  float vals[2] = {a, f};
  float norms[2];
#pragma unroll
  for (int which = 0; which < 2; ++which) {
    float x = vals[which];
    red[t] = x;
    __syncthreads();
    for (int o = 64; o > 0; o >>= 1) {
      if (t < o) red[t] += red[t + o];
      __syncthreads();
    }
    float mean = red[0] / 128.f;
    __syncthreads();
    float d = x - mean;
    red[t] = d * d;
    __syncthreads();
    for (int o = 64; o > 0; o >>= 1) {
      if (t < o) red[t] += red[t + o];
      __syncthreads();
    }
    float stdv = sqrtf(red[0] / 127.f);  // ddof=1
    __syncthreads();
    float z = d / stdv;
    red[t] = z;
    __syncthreads();
    for (int o = 64; o > 0; o >>= 1) {
      if (t < o) red[t] = fminf(red[t], red[t + o]);
      __syncthreads();
    }
    float zmin = red[0];
    __syncthreads();
    red[t] = z;
    __syncthreads();
    for (int o = 64; o > 0; o >>= 1) {
      if (t < o) red[t] = fmaxf(red[t], red[t + o]);
      __syncthreads();
    }
    float zmax = red[0];
    __syncthreads();
    norms[which] = (z - zmin) / (zmax - zmin);
  }

  emb[t] = norms[0] + norms[1];
  __syncthreads();
  if (t < ncls) {
    float acc = b_cls[t];
    for (int k = 0; k < 128; ++k) acc = fmaf(emb[k], W_cls[k * ncls + t], acc);
    out[t] = acc;
  }
}

extern "C" void kernel_launch(void* const* d_in, const int* in_sizes, int n_in,
                              void* d_out, int out_size, void* d_ws, size_t ws_size,
                              hipStream_t stream) {
  const float* apig_feat = (const float*)d_in[0];
  const float* fcg_feat = (const float*)d_in[1];
  const float* W_a1 = (const float*)d_in[2];
  const float* b_a1 = (const float*)d_in[3];
  const float* W_a2 = (const float*)d_in[4];
  const float* b_a2 = (const float*)d_in[5];
  const float* W_f1 = (const float*)d_in[6];
  const float* b_f1 = (const float*)d_in[7];
  const float* W_f2 = (const float*)d_in[8];
  const float* b_f2 = (const float*)d_in[9];
  const float* W1 = (const float*)d_in[10];
  const float* b1 = (const float*)d_in[11];
  const float* W2 = (const float*)d_in[12];
  const float* b2 = (const float*)d_in[13];
  // d_in[14]/d_in[15] (W_attn, b_attn): dead — softmax over length-1 axis == 1.
  const float* W_cls = (const float*)d_in[16];
  const float* b_cls = (const float*)d_in[17];
  const int* a_src = (const int*)d_in[18];
  const int* a_dst = (const int*)d_in[19];
  const int* f_src = (const int*)d_in[20];
  const int* f_dst = (const int*)d_in[21];

  const int hidden = in_sizes[3];             // 128
  const int united = in_sizes[11];            // 64
  const int ncls = in_sizes[17];              // 10
  const int apig_dim = in_sizes[2] / hidden;  // 256
  const int fcg_dim = in_sizes[6] / hidden;   // 128
  const int n_a = in_sizes[0] / apig_dim;     // 50000
  const int n_f = in_sizes[1] / fcg_dim;      // 100000
  const int e_a = in_sizes[18];               // 800000
  const int e_f = in_sizes[20];               // 1600000

  // ---- workspace carve-up (all 256B aligned) ----
  char* w = (char*)d_ws;
  auto alloc = [&](size_t bytes) -> void* {
    void* p = (void*)w;
    w += (bytes + 255) & ~(size_t)255;
    return p;
  };
  const int E_tot = e_a + e_f;
  const int B = (E_tot + SORT_T - 1) / SORT_T;
  const int nblkA = (n_a + 7) / 8, nblkF = (n_f + 7) / 8;

  float* isr_out_a = (float*)alloc((size_t)n_a * 4);
  float* isr_in_a = (float*)alloc((size_t)n_a * 4);
  float* isr_out_f = (float*)alloc((size_t)n_f * 4);
  float* isr_in_f = (float*)alloc((size_t)n_f * 4);
  int* offs_a = (int*)alloc((size_t)(n_a + 1) * 4);
  int* offs_f = (int*)alloc((size_t)(n_f + 1) * 4);
  int* offs_src_a = (int*)alloc((size_t)(n_a + 1) * 4);
  int* offs_src_f = (int*)alloc((size_t)(n_f + 1) * 4);
  int* kp = (int*)alloc((size_t)E_tot * 4);                      // dst-sort packed
  unsigned short* okey = (unsigned short*)alloc((size_t)E_tot * 2);  // src-sort keys
  int* csr = (int*)alloc((size_t)E_tot * 4);  // final CSR (apig [0,e_a), fcg rest)
  int* blkhistD = (int*)alloc((size_t)512 * B * 4);
  int* blkhistS = (int*)alloc((size_t)512 * B * 4);
  int* bintotalD = (int*)alloc((size_t)512 * 4);
  int* bintotalS = (int*)alloc((size_t)512 * 4);
  unsigned short* G_a = (unsigned short*)alloc((size_t)n_a * hidden * 2);  // bf16 table
  unsigned short* H_a = (unsigned short*)alloc((size_t)n_a * hidden * 2);  // h1 / a_dec
  unsigned short* G_f = (unsigned short*)alloc((size_t)n_f * hidden * 2);
  unsigned short* H_f = (unsigned short*)alloc((size_t)n_f * hidden * 2);
  float* P_a = (float*)alloc((size_t)nblkA * hidden * 4);  // conv2 block partials
  float* P_f = (float*)alloc((size_t)nblkF * hidden * 4);
  unsigned short* E_a = G_a;  // enc raw (bf16, n x 64) aliases G_a (disjoint lifetimes)
  unsigned short* E_f = G_f;
  float* a_sum = (float*)alloc((size_t)united * 4);
  float* f_sum = (float*)alloc((size_t)united * 4);
  float* emb_a = (float*)alloc((size_t)hidden * 4);
  unsigned* emb_f = (unsigned*)alloc((size_t)hidden * 4);
  // bf16 [N][K] pre-transposed weights
  unsigned short* T_a1 = (unsigned short*)alloc((size_t)apig_dim * hidden * 2);
  unsigned short* T_f1 = (unsigned short*)alloc((size_t)fcg_dim * hidden * 2);
  unsigned short* T_a2 = (unsigned short*)alloc((size_t)hidden * hidden * 2);
  unsigned short* T_f2 = (unsigned short*)alloc((size_t)hidden * hidden * 2);
  unsigned short* T1 = (unsigned short*)alloc((size_t)hidden * united * 2);
  unsigned short* T2 = (unsigned short*)alloc((size_t)united * hidden * 2);
  int* csr_a = csr;
  int* csr_f = csr + e_a;
  (void)ws_size;
  (void)n_in;
  (void)out_size;

  dim3 blk(256);

  // 1) init (zero accumulators + sentinels) + weight transpose prep
  prep_init_kernel<<<dim3(32, 6), blk, 0, stream>>>(
      W_a1, W_f1, W_a2, W_f2, W1, W2, T_a1, T_f1, T_a2, T_f2, T1, T2,
      a_sum, f_sum, united, emb_a, emb_f, hidden,
      offs_a, offs_src_a, n_a, e_a, offs_f, offs_src_f, n_f, e_f);

  // 2-5) fused CSR build (dst+src sorted in one pipeline)
  hist2_kernel<<<B, blk, 0, stream>>>(a_dst, f_dst, a_src, f_src, e_a, E_tot,
                                      blkhistD, blkhistS, B);
  cursor2_kernel<<<1024, blk, 0, stream>>>(blkhistD, blkhistS, B, bintotalD, bintotalS);
  scatter2_kernel<<<B, blk, 0, stream>>>(a_dst, f_dst, a_src, f_src, e_a, E_tot,
                                         blkhistD, blkhistS, B, bintotalD, bintotalS,
                                         kp, okey);
  bucket2_kernel<<<1024, blk, 0, stream>>>(kp, okey, bintotalD, bintotalS, E_tot, e_a,
                                           csr, offs_a, n_a, offs_f, n_f,
                                           offs_src_a, offs_src_f);
  // 6) degrees -> isr
  isr_kernel<<<(n_f + 255) / 256, blk, 0, stream>>>(offs_a, offs_src_a, isr_out_a, isr_in_a,
                                                    n_a, offs_f, offs_src_f, isr_out_f,
                                                    isr_in_f, n_f);

  const int ga = (n_a + 63) / 64, gf = (n_f + 63) / 64;

  // 7-8) conv1 GEMMs (per graph: K differs)
  gemm_bls_kernel<256, 128, 0, 0><<<ga, blk, 0, stream>>>(
      apig_feat, T_a1, G_a, n_a, nullptr, 0.f, isr_out_a, nullptr);
  gemm_bls_kernel<128, 128, 0, 0><<<gf, blk, 0, stream>>>(
      fcg_feat, T_f1, G_f, n_f, nullptr, 0.f, isr_out_f, nullptr);
  // 9) conv1 aggregation (both graphs, mode 0)
  agg2_kernel<<<nblkA + nblkF, blk, 0, stream>>>(
      G_a, offs_a, csr_a, isr_in_a, b_a1, H_a, n_a, 0,
      G_f, offs_f, csr_f, isr_in_f, b_f1, H_f, n_f, 0, nblkA);
  // 10) enc GEMM (merged): E = H @ W1 + b1
  gemm_bls2_kernel<128, 64, 1, 0><<<ga + gf, blk, 0, stream>>>(
      H_a, T1, E_a, n_a, H_f, T1, E_f, n_f,
      nullptr, nullptr, 0.f, nullptr, nullptr, b1, ga);
  // 11) colsums of E (merged)
  colsum2_kernel<<<512, blk, 0, stream>>>(E_a, a_sum, n_a, E_f, f_sum, n_f, united);
  // 12) dec GEMM (merged): H = (E + 0.1*cross_sum) @ W2 + b2
  gemm_bls2_kernel<64, 128, 1, 1><<<ga + gf, blk, 0, stream>>>(
      E_a, T2, H_a, n_a, E_f, T2, H_f, n_f,
      f_sum, a_sum, 0.1f, nullptr, nullptr, b2, ga);
  // 13) conv2 GEMM (merged): G = (dec @ W_x2) * isr_out
  gemm_bls2_kernel<128, 128, 1, 0><<<ga + gf, blk, 0, stream>>>(
      H_a, T_a2, G_a, n_a, H_f, T_f2, G_f, n_f,
      nullptr, nullptr, 0.f, isr_out_a, isr_out_f, nullptr, ga);
  // 14) conv2 aggregation + per-block reductions (apig sum, fcg max)
  agg2_kernel<<<nblkA + nblkF, blk, 0, stream>>>(
      G_a, offs_a, csr_a, isr_in_a, b_a2, P_a, n_a, 1,
      G_f, offs_f, csr_f, isr_in_f, b_f2, P_f, n_f, 2, nblkA);
  // 15) final P reductions (merged sum+max)
  colfin_kernel<<<512, blk, 0, stream>>>(P_a, emb_a, nblkA, P_f, emb_f, nblkF, hidden);
  // 16) head
  final_kernel<<<1, 128, 0, stream>>>(emb_a, emb_f, W_cls, b_cls, (float*)d_out,
                                      1.0f / (float)n_a, ncls);
}